// Round 1
// baseline (499.447 us; speedup 1.0000x reference)
//
#include <hip/hip_runtime.h>
#include <hip/hip_bf16.h>
#include <stdint.h>

// Problem constants (B=2, S=2048, D=1024, H=16, DK=64, FF=4096)
#define B_   2
#define S_   2048
#define D_   1024
#define H_   16
#define FF_  4096
#define TOK  4096        // B*S
#define EPS_ 1e-5f

typedef __attribute__((ext_vector_type(8))) short short8;
typedef __attribute__((ext_vector_type(4))) short short4_t;
typedef __attribute__((ext_vector_type(4))) float float4_t;

__device__ __forceinline__ short f2bf(float f) {
  union { float f; uint32_t u; } v; v.f = f;
  uint32_t r = v.u + 0x7fffu + ((v.u >> 16) & 1u);
  return (short)(r >> 16);
}

__device__ __forceinline__ void gload_lds16(const void* g, void* l) {
  __builtin_amdgcn_global_load_lds(
      (const __attribute__((address_space(1))) void*)g,
      (__attribute__((address_space(3))) void*)l, 16, 0, 0);
}

// ---------------- fp32 -> bf16 conversion (grid-stride, vectorized) --------
__global__ void cvt_kernel(const float* __restrict__ in, short* __restrict__ out, int n) {
  int idx = blockIdx.x * blockDim.x + threadIdx.x;
  int stride = gridDim.x * blockDim.x;
  for (int j = idx * 4; j < n; j += stride * 4) {
    float4_t v = *(const float4_t*)(in + j);
    short4_t o = { f2bf(v[0]), f2bf(v[1]), f2bf(v[2]), f2bf(v[3]) };
    *(short4_t*)(out + j) = o;
  }
}

// ---------------- LayerNorm (ddof=1, divide by std+eps), f32 in, bf16 out --
__global__ __launch_bounds__(256) void ln_kernel(
    const float* __restrict__ x, const float* __restrict__ alpha,
    const float* __restrict__ beta, short* __restrict__ out)
{
  const int row = blockIdx.x;
  const int tid = threadIdx.x;
  const float4_t v = *(const float4_t*)(x + (size_t)row * D_ + tid * 4);
  float s  = v[0] + v[1] + v[2] + v[3];
  float ss = v[0]*v[0] + v[1]*v[1] + v[2]*v[2] + v[3]*v[3];
  #pragma unroll
  for (int m = 1; m < 64; m <<= 1) { s += __shfl_xor(s, m); ss += __shfl_xor(ss, m); }
  __shared__ float red[8];
  const int wave = tid >> 6, lane = tid & 63;
  if (lane == 0) { red[wave] = s; red[4 + wave] = ss; }
  __syncthreads();
  s  = red[0] + red[1] + red[2] + red[3];
  ss = red[4] + red[5] + red[6] + red[7];
  const float mean = s * (1.0f / D_);
  float var = (ss - (float)D_ * mean * mean) * (1.0f / (D_ - 1));
  var = fmaxf(var, 0.0f);
  const float inv = 1.0f / (sqrtf(var) + EPS_);
  short4_t o;
  #pragma unroll
  for (int j = 0; j < 4; j++) {
    float a = alpha[tid*4 + j], bb = beta[tid*4 + j];
    o[j] = f2bf((v[j] - mean) * inv * a + bb);
  }
  *(short4_t*)(out + (size_t)row * D_ + tid * 4) = o;
}

// ---------------- GEMM: C(MxN) = A(MxK) * B(NxK)^T, bf16 in, epilogues -----
// EPI 0: +bias[col] -> bf16     (QK projections)
// EPI 1: +bias[row] -> bf16     (V^T = Wv * h1^T; bias indexed by out feature=row)
// EPI 2: relu(+bias[col]) -> bf16  (FF1)
// EPI 3: res + C + bias[col] -> fp32  (WO, FF2)
template<int EPI>
__global__ __launch_bounds__(256) void gemm_bt(
    const short* __restrict__ A, const short* __restrict__ Bm,
    void* __restrict__ Cout, const float* __restrict__ bias,
    const float* __restrict__ res, int M, int N, int K)
{
  __shared__ __align__(16) short As[128][32];
  __shared__ __align__(16) short Bs[128][32];

  const int tid  = threadIdx.x;
  const int wave = tid >> 6, lane = tid & 63;
  const int l15  = lane & 15, l4 = lane >> 4;
  const int m0 = blockIdx.y * 128, n0 = blockIdx.x * 128;
  const int wr = wave >> 1, wc = wave & 1;

  float4_t acc[4][4] = {};

  // staging addresses: wave w stages rows [w*32, w*32+32) of each tile,
  // two global_load_lds issues of 16 rows each (lane l -> row l/4, 16B chunk l%4)
  const int scol = (lane & 3) * 8;
  const short* gA0 = A  + (size_t)(m0 + wave*32 + (lane >> 2)) * K + scol;
  const short* gB0 = Bm + (size_t)(n0 + wave*32 + (lane >> 2)) * K + scol;
  const short* gA1 = gA0 + (size_t)16 * K;
  const short* gB1 = gB0 + (size_t)16 * K;

  for (int k0 = 0; k0 < K; k0 += 32) {
    gload_lds16(gA0 + k0, &As[wave*32][0]);
    gload_lds16(gA1 + k0, &As[wave*32 + 16][0]);
    gload_lds16(gB0 + k0, &Bs[wave*32][0]);
    gload_lds16(gB1 + k0, &Bs[wave*32 + 16][0]);
    __syncthreads();   // drains vmcnt -> LDS tiles ready

    short8 af[4], bf[4];
    #pragma unroll
    for (int i = 0; i < 4; i++)
      af[i] = *(const short8*)&As[wr*64 + i*16 + l15][l4*8];
    #pragma unroll
    for (int i = 0; i < 4; i++)
      bf[i] = *(const short8*)&Bs[wc*64 + i*16 + l15][l4*8];
    #pragma unroll
    for (int mi = 0; mi < 4; mi++)
      #pragma unroll
      for (int ni = 0; ni < 4; ni++)
        acc[mi][ni] = __builtin_amdgcn_mfma_f32_16x16x32_bf16(af[mi], bf[ni], acc[mi][ni], 0, 0, 0);
    __syncthreads();   // all waves done reading before next stage overwrites
  }

  // epilogue: C/D layout col=lane&15, row=(lane>>4)*4+reg
  const int crow0 = m0 + wr*64 + l4*4;
  const int ccol0 = n0 + wc*64 + l15;
  #pragma unroll
  for (int mi = 0; mi < 4; mi++) {
    #pragma unroll
    for (int ni = 0; ni < 4; ni++) {
      const int col = ccol0 + ni*16;
      const float bc = (EPI == 1) ? 0.0f : bias[col];
      #pragma unroll
      for (int r = 0; r < 4; r++) {
        const int row = crow0 + mi*16 + r;
        const float v = acc[mi][ni][r];
        if (EPI == 0) {
          ((short*)Cout)[(size_t)row * N + col] = f2bf(v + bc);
        } else if (EPI == 1) {
          ((short*)Cout)[(size_t)row * N + col] = f2bf(v + bias[row]);
        } else if (EPI == 2) {
          ((short*)Cout)[(size_t)row * N + col] = f2bf(fmaxf(v + bc, 0.0f));
        } else {
          ((float*)Cout)[(size_t)row * N + col] = res[(size_t)row * N + col] + v + bc;
        }
      }
    }
  }
}

// ---------------- Flash attention ------------------------------------------
// qk: (TOK x 2048) bf16, Q at cols [0,1024), K at cols [1024,2048) (col = h*64+d)
// vt: (1024 x TOK) bf16, vt[h*64+d][b*S+s] = V[b,s,h*64+d]
// out: (TOK x 1024) bf16 attention output (pre-WO)
__global__ __launch_bounds__(256) void attn_kernel(
    const short* __restrict__ qk, const short* __restrict__ vt,
    const int* __restrict__ mask, short* __restrict__ out)
{
  const int qt = blockIdx.x, h = blockIdx.y, b = blockIdx.z;
  const int tid = threadIdx.x, wave = tid >> 6, lane = tid & 63;
  const int l15 = lane & 15, l4 = lane >> 4;
  const int q0 = qt * 64 + wave * 16;

  __shared__ __align__(16) short plds[4][16][40];  // per-wave P tile, stride 40 (bank-spread)
  short* pw = &plds[wave][0][0];

  // Q fragments (A operand): lane -> row l15, k = l4*8.., two K-chunks of 32
  short8 qa[2];
  #pragma unroll
  for (int kc = 0; kc < 2; kc++)
    qa[kc] = *(const short8*)&qk[(size_t)(b*S_ + q0 + l15) * 2048 + h*64 + kc*32 + l4*8];

  float4_t acc[4];
  #pragma unroll
  for (int i = 0; i < 4; i++) acc[i] = (float4_t){0.f, 0.f, 0.f, 0.f};
  float mrow[4] = {-1e30f, -1e30f, -1e30f, -1e30f};
  float lsum[4] = {0.f, 0.f, 0.f, 0.f};

  for (int kt = 0; kt < S_ / 32; kt++) {
    // S = Q K^T for 32 keys (2 col-groups of 16)
    float4_t sc[2] = {(float4_t){0,0,0,0}, (float4_t){0,0,0,0}};
    #pragma unroll
    for (int ng = 0; ng < 2; ng++)
      #pragma unroll
      for (int kc = 0; kc < 2; kc++) {
        short8 kf = *(const short8*)&qk[(size_t)(b*S_ + kt*32 + ng*16 + l15) * 2048
                                        + 1024 + h*64 + kc*32 + l4*8];
        sc[ng] = __builtin_amdgcn_mfma_f32_16x16x32_bf16(qa[kc], kf, sc[ng], 0, 0, 0);
      }
    // scale 1/sqrt(64) + mask
    #pragma unroll
    for (int ng = 0; ng < 2; ng++) {
      const int kidx = kt*32 + ng*16 + l15;
      const bool keep = mask[b*S_ + kidx] != 0;
      #pragma unroll
      for (int r = 0; r < 4; r++) {
        float s = sc[ng][r] * 0.125f;
        sc[ng][r] = keep ? s : -1e30f;
      }
    }
    // online softmax: row r lives in 16 lanes (col dim), reg r
    float mn[4], esc[4];
    #pragma unroll
    for (int r = 0; r < 4; r++) {
      float pm = fmaxf(sc[0][r], sc[1][r]);
      #pragma unroll
      for (int mm = 1; mm < 16; mm <<= 1) pm = fmaxf(pm, __shfl_xor(pm, mm));
      mn[r]  = fmaxf(mrow[r], pm);
      esc[r] = __expf(mrow[r] - mn[r]);
      mrow[r] = mn[r];
    }
    #pragma unroll
    for (int ng = 0; ng < 2; ng++)
      #pragma unroll
      for (int r = 0; r < 4; r++)
        sc[ng][r] = __expf(sc[ng][r] - mn[r]);
    #pragma unroll
    for (int r = 0; r < 4; r++) {
      float ts = sc[0][r] + sc[1][r];
      #pragma unroll
      for (int mm = 1; mm < 16; mm <<= 1) ts += __shfl_xor(ts, mm);
      lsum[r] = lsum[r] * esc[r] + ts;
    }
    #pragma unroll
    for (int dg = 0; dg < 4; dg++)
      #pragma unroll
      for (int r = 0; r < 4; r++)
        acc[dg][r] *= esc[r];
    // P (C/D layout) -> LDS -> A-fragment layout
    #pragma unroll
    for (int ng = 0; ng < 2; ng++)
      #pragma unroll
      for (int r = 0; r < 4; r++)
        pw[(l4*4 + r) * 40 + ng*16 + l15] = f2bf(sc[ng][r]);
    short8 pf = *(const short8*)&pw[l15 * 40 + l4 * 8];
    // O += P V
    #pragma unroll
    for (int dg = 0; dg < 4; dg++) {
      short8 vf = *(const short8*)&vt[(size_t)(h*64 + dg*16 + l15) * TOK + b*S_ + kt*32 + l4*8];
      acc[dg] = __builtin_amdgcn_mfma_f32_16x16x32_bf16(pf, vf, acc[dg], 0, 0, 0);
    }
  }
  #pragma unroll
  for (int dg = 0; dg < 4; dg++)
    #pragma unroll
    for (int r = 0; r < 4; r++) {
      float ov = acc[dg][r] / lsum[r];
      out[(size_t)(b*S_ + q0 + l4*4 + r) * D_ + h*64 + dg*16 + l15] = f2bf(ov);
    }
}

// ---------------------------------------------------------------------------
extern "C" void kernel_launch(void* const* d_in, const int* in_sizes, int n_in,
                              void* d_out, int out_size, void* d_ws, size_t ws_size,
                              hipStream_t stream)
{
  const float* x     = (const float*)d_in[0];
  const int*   mask  = (const int*)d_in[1];
  const float* wq_w  = (const float*)d_in[2];
  const float* wq_b  = (const float*)d_in[3];
  const float* wk_w  = (const float*)d_in[4];
  const float* wk_b  = (const float*)d_in[5];
  const float* wv_w  = (const float*)d_in[6];
  const float* wv_b  = (const float*)d_in[7];
  const float* wo_w  = (const float*)d_in[8];
  const float* wo_b  = (const float*)d_in[9];
  const float* ff1_w = (const float*)d_in[10];
  const float* ff1_b = (const float*)d_in[11];
  const float* ff2_w = (const float*)d_in[12];
  const float* ff2_b = (const float*)d_in[13];
  const float* ln1_a = (const float*)d_in[14];
  const float* ln1_b = (const float*)d_in[15];
  const float* ln2_a = (const float*)d_in[16];
  const float* ln2_b = (const float*)d_in[17];

  uint8_t* ws = (uint8_t*)d_ws;
  const size_t MB = 1024 * 1024;
  short* wqk   = (short*)(ws + 0);        // (2048,1024) bf16: [wq; wk]      4 MB
  short* wvb   = (short*)(ws + 4*MB);     // (1024,1024)                     2 MB
  short* wob   = (short*)(ws + 6*MB);     // (1024,1024)                     2 MB
  short* ff1b  = (short*)(ws + 8*MB);     // (4096,1024)                     8 MB
  short* ff2b  = (short*)(ws + 16*MB);    // (1024,4096)                     8 MB
  float* bqk   = (float*)(ws + 24*MB);    // 2048 fp32 concat bias           8 KB
  short* h1    = (short*)(ws + 25*MB);    // (4096,1024) bf16 (h1, later h2) 8 MB
  short* qkbuf = (short*)(ws + 33*MB);    // (4096,2048) bf16               16 MB
  short* vt    = (short*)(ws + 49*MB);    // (1024,4096) bf16                8 MB
  short* attno = (short*)(ws + 57*MB);    // (4096,1024) bf16                8 MB
  float* x2    = (float*)(ws + 65*MB);    // (4096,1024) fp32               16 MB
  short* ffa   = (short*)(ws + 33*MB);    // (4096,4096) bf16, reuses qkbuf/vt/attno (dead by then)

  // 1) weights -> bf16 (every launch; deterministic, ~13us)
  cvt_kernel<<<1024, 256, 0, stream>>>(wq_w, wqk,             1024*1024);
  cvt_kernel<<<1024, 256, 0, stream>>>(wk_w, wqk + 1024*1024, 1024*1024);
  cvt_kernel<<<1024, 256, 0, stream>>>(wv_w, wvb,             1024*1024);
  cvt_kernel<<<1024, 256, 0, stream>>>(wo_w, wob,             1024*1024);
  cvt_kernel<<<2048, 256, 0, stream>>>(ff1_w, ff1b,           4096*1024);
  cvt_kernel<<<2048, 256, 0, stream>>>(ff2_w, ff2b,           4096*1024);
  hipMemcpyAsync(bqk,        wq_b, 1024*sizeof(float), hipMemcpyDeviceToDevice, stream);
  hipMemcpyAsync(bqk + 1024, wk_b, 1024*sizeof(float), hipMemcpyDeviceToDevice, stream);

  // 2) LN1: x -> h1 (bf16)
  ln_kernel<<<TOK, 256, 0, stream>>>(x, ln1_a, ln1_b, h1);

  // 3) [Q|K] = h1 @ [wq;wk]^T + b     (4096 x 2048)
  gemm_bt<0><<<dim3(2048/128, TOK/128), 256, 0, stream>>>(h1, wqk, qkbuf, bqk, nullptr, TOK, 2048, 1024);

  // 4) V^T = wv @ h1^T + bv[row]      (1024 x 4096)
  gemm_bt<1><<<dim3(TOK/128, 1024/128), 256, 0, stream>>>(wvb, h1, vt, wv_b, nullptr, 1024, TOK, 1024);

  // 5) flash attention -> attno (bf16)
  attn_kernel<<<dim3(S_/64, H_, B_), 256, 0, stream>>>(qkbuf, vt, mask, attno);

  // 6) x2 = x + attno @ wo^T + bo     (fp32)
  gemm_bt<3><<<dim3(1024/128, TOK/128), 256, 0, stream>>>(attno, wob, x2, wo_b, x, TOK, 1024, 1024);

  // 7) LN2: x2 -> h2 (reuse h1 buffer)
  ln_kernel<<<TOK, 256, 0, stream>>>(x2, ln2_a, ln2_b, h1);

  // 8) ffa = relu(h2 @ ff1^T + b1)    (4096 x 4096 bf16)
  gemm_bt<2><<<dim3(FF_/128, TOK/128), 256, 0, stream>>>(h1, ff1b, ffa, ff1_b, nullptr, TOK, FF_, 1024);

  // 9) out = x2 + ffa @ ff2^T + b2    (fp32)
  gemm_bt<3><<<dim3(1024/128, TOK/128), 256, 0, stream>>>(ffa, ff2b, (float*)d_out, ff2_b, x2, TOK, 1024, FF_);
}

// Round 2
// 367.508 us; speedup vs baseline: 1.3590x; 1.3590x over previous
//
#include <hip/hip_runtime.h>
#include <hip/hip_bf16.h>
#include <stdint.h>

// Problem constants (B=2, S=2048, D=1024, H=16, DK=64, FF=4096)
#define B_   2
#define S_   2048
#define D_   1024
#define H_   16
#define FF_  4096
#define TOK  4096        // B*S
#define EPS_ 1e-5f

typedef __attribute__((ext_vector_type(8))) short short8;
typedef __attribute__((ext_vector_type(4))) short short4_t;
typedef __attribute__((ext_vector_type(4))) float float4_t;

__device__ __forceinline__ short f2bf(float f) {
  union { float f; uint32_t u; } v; v.f = f;
  uint32_t r = v.u + 0x7fffu + ((v.u >> 16) & 1u);
  return (short)(r >> 16);
}

__device__ __forceinline__ uint32_t pack2bf(float a, float b) {
  return (uint32_t)(uint16_t)f2bf(a) | ((uint32_t)(uint16_t)f2bf(b) << 16);
}

__device__ __forceinline__ void gload_lds16(const void* g, void* l) {
  __builtin_amdgcn_global_load_lds(
      (const __attribute__((address_space(1))) void*)g,
      (__attribute__((address_space(3))) void*)l, 16, 0, 0);
}

// ---------------- fp32 -> bf16 conversion (grid-stride, vectorized) --------
__global__ void cvt_kernel(const float* __restrict__ in, short* __restrict__ out, int n) {
  int idx = blockIdx.x * blockDim.x + threadIdx.x;
  int stride = gridDim.x * blockDim.x;
  for (int j = idx * 4; j < n; j += stride * 4) {
    float4_t v = *(const float4_t*)(in + j);
    short4_t o = { f2bf(v[0]), f2bf(v[1]), f2bf(v[2]), f2bf(v[3]) };
    *(short4_t*)(out + j) = o;
  }
}

// ---------------- mask -> additive bias ------------------------------------
__global__ void maskb_kernel(const int* __restrict__ m, float* __restrict__ o, int n) {
  int i = blockIdx.x * blockDim.x + threadIdx.x;
  if (i < n) o[i] = m[i] ? 0.0f : -1e30f;
}

// ---------------- LayerNorm (ddof=1, divide by std+eps), f32 in, bf16 out --
__global__ __launch_bounds__(256) void ln_kernel(
    const float* __restrict__ x, const float* __restrict__ alpha,
    const float* __restrict__ beta, short* __restrict__ out)
{
  const int row = blockIdx.x;
  const int tid = threadIdx.x;
  const float4_t v = *(const float4_t*)(x + (size_t)row * D_ + tid * 4);
  float s  = v[0] + v[1] + v[2] + v[3];
  float ss = v[0]*v[0] + v[1]*v[1] + v[2]*v[2] + v[3]*v[3];
  #pragma unroll
  for (int m = 1; m < 64; m <<= 1) { s += __shfl_xor(s, m); ss += __shfl_xor(ss, m); }
  __shared__ float red[8];
  const int wave = tid >> 6, lane = tid & 63;
  if (lane == 0) { red[wave] = s; red[4 + wave] = ss; }
  __syncthreads();
  s  = red[0] + red[1] + red[2] + red[3];
  ss = red[4] + red[5] + red[6] + red[7];
  const float mean = s * (1.0f / D_);
  float var = (ss - (float)D_ * mean * mean) * (1.0f / (D_ - 1));
  var = fmaxf(var, 0.0f);
  const float inv = 1.0f / (sqrtf(var) + EPS_);
  short4_t o;
  #pragma unroll
  for (int j = 0; j < 4; j++) {
    float a = alpha[tid*4 + j], bb = beta[tid*4 + j];
    o[j] = f2bf((v[j] - mean) * inv * a + bb);
  }
  *(short4_t*)(out + (size_t)row * D_ + tid * 4) = o;
}

// ---------------- GEMM: C(MxN) = A(MxK) * B(NxK)^T, bf16 in, epilogues -----
// EPI 0: +bias[col] -> bf16     (QK projections)
// EPI 1: +bias[row] -> bf16     (V^T = Wv * h1^T; bias indexed by out feature=row)
// EPI 2: relu(+bias[col]) -> bf16  (FF1)
// EPI 3: res + C + bias[col] -> fp32  (WO, FF2)
template<int EPI>
__global__ __launch_bounds__(256) void gemm_bt(
    const short* __restrict__ A, const short* __restrict__ Bm,
    void* __restrict__ Cout, const float* __restrict__ bias,
    const float* __restrict__ res, int M, int N, int K)
{
  __shared__ __align__(16) short As[128][32];
  __shared__ __align__(16) short Bs[128][32];

  const int tid  = threadIdx.x;
  const int wave = tid >> 6, lane = tid & 63;
  const int l15  = lane & 15, l4 = lane >> 4;
  const int m0 = blockIdx.y * 128, n0 = blockIdx.x * 128;
  const int wr = wave >> 1, wc = wave & 1;

  float4_t acc[4][4] = {};

  const int scol = (lane & 3) * 8;
  const short* gA0 = A  + (size_t)(m0 + wave*32 + (lane >> 2)) * K + scol;
  const short* gB0 = Bm + (size_t)(n0 + wave*32 + (lane >> 2)) * K + scol;
  const short* gA1 = gA0 + (size_t)16 * K;
  const short* gB1 = gB0 + (size_t)16 * K;

  for (int k0 = 0; k0 < K; k0 += 32) {
    gload_lds16(gA0 + k0, &As[wave*32][0]);
    gload_lds16(gA1 + k0, &As[wave*32 + 16][0]);
    gload_lds16(gB0 + k0, &Bs[wave*32][0]);
    gload_lds16(gB1 + k0, &Bs[wave*32 + 16][0]);
    __syncthreads();

    short8 af[4], bf[4];
    #pragma unroll
    for (int i = 0; i < 4; i++)
      af[i] = *(const short8*)&As[wr*64 + i*16 + l15][l4*8];
    #pragma unroll
    for (int i = 0; i < 4; i++)
      bf[i] = *(const short8*)&Bs[wc*64 + i*16 + l15][l4*8];
    #pragma unroll
    for (int mi = 0; mi < 4; mi++)
      #pragma unroll
      for (int ni = 0; ni < 4; ni++)
        acc[mi][ni] = __builtin_amdgcn_mfma_f32_16x16x32_bf16(af[mi], bf[ni], acc[mi][ni], 0, 0, 0);
    __syncthreads();
  }

  const int crow0 = m0 + wr*64 + l4*4;
  const int ccol0 = n0 + wc*64 + l15;
  #pragma unroll
  for (int mi = 0; mi < 4; mi++) {
    #pragma unroll
    for (int ni = 0; ni < 4; ni++) {
      const int col = ccol0 + ni*16;
      const float bc = (EPI == 1) ? 0.0f : bias[col];
      #pragma unroll
      for (int r = 0; r < 4; r++) {
        const int row = crow0 + mi*16 + r;
        const float v = acc[mi][ni][r];
        if (EPI == 0) {
          ((short*)Cout)[(size_t)row * N + col] = f2bf(v + bc);
        } else if (EPI == 1) {
          ((short*)Cout)[(size_t)row * N + col] = f2bf(v + bias[row]);
        } else if (EPI == 2) {
          ((short*)Cout)[(size_t)row * N + col] = f2bf(fmaxf(v + bc, 0.0f));
        } else {
          ((float*)Cout)[(size_t)row * N + col] = res[(size_t)row * N + col] + v + bc;
        }
      }
    }
  }
}

// ---------------- Flash attention (swapped QK^T, LDS-staged K/V) -----------
// qk: (TOK x 2048) bf16, Q cols [0,1024), K cols [1024,2048)  (col = h*64+d)
// vt: (1024 x TOK) bf16, vt[h*64+d][b*S+s] = V[b,s,h*64+d]
// maskb: (TOK) fp32 additive bias (0 or -1e30), per key
// out: (TOK x 1024) bf16 attention output (pre-WO)
// Block: 4 waves x 32 q-rows = 128 q-rows, one (b,h). KVBLK=64, double-buffered.
#define SC2 0.18033688f   // (1/8) * log2(e)

__global__ __launch_bounds__(256, 2) void attn_kernel(
    const short* __restrict__ qk, const short* __restrict__ vt,
    const float* __restrict__ maskb, short* __restrict__ out)
{
  const int qt = blockIdx.x, h = blockIdx.y, b = blockIdx.z;
  const int tid = threadIdx.x, wave = tid >> 6, lane = tid & 63;
  const int l15 = lane & 15, l4 = lane >> 4, l7 = l15 & 7;
  const int q0 = qt * 128 + wave * 32;

  // K tile [64 keys][64 dk], V^T tile [64 d][64 keys], both XOR-swizzled:
  // LDS 16B-chunk c of row r holds global chunk c ^ (r&7).
  __shared__ __align__(16) short Kt[2][4096];
  __shared__ __align__(16) short Vt[2][4096];
  __shared__ __align__(16) uint32_t pbu[4][32][32];   // per-wave P (bf16 pairs), swizzled

  // Q fragments (held in registers for the whole kernel)
  short8 qa[2][2];
  #pragma unroll
  for (int mq = 0; mq < 2; mq++)
    #pragma unroll
    for (int kc = 0; kc < 2; kc++)
      qa[mq][kc] = *(const short8*)&qk[(size_t)(b*S_ + q0 + mq*16 + l15) * 2048 + h*64 + kc*32 + l4*8];

  float4_t acc[2][4];
  #pragma unroll
  for (int mq = 0; mq < 2; mq++)
    #pragma unroll
    for (int dg = 0; dg < 4; dg++)
      acc[mq][dg] = (float4_t){0.f, 0.f, 0.f, 0.f};
  float m2[2]   = {-1e30f, -1e30f};
  float lsum[2] = {0.f, 0.f};

  // staging geometry: slot = i*256 + wave*64 + lane; row = slot>>3; chunk = lane&7
  // source chunk pre-swizzled: ch = (lane&7) ^ (row&7), row&7 == lane>>3
  const int r8 = lane >> 3;
  const int ch = (lane & 7) ^ r8;
  const int sbase = wave * 512;   // shorts

  // prologue: stage tile 0 into buffer 0
  #pragma unroll
  for (int i = 0; i < 2; i++) {
    const int row = i*32 + wave*8 + r8;
    gload_lds16(qk + (size_t)(b*S_ + row) * 2048 + 1024 + h*64 + ch*8, &Kt[0][sbase + i*2048]);
    gload_lds16(vt + (size_t)(h*64 + row) * TOK + b*S_ + ch*8,         &Vt[0][sbase + i*2048]);
  }

  for (int t = 0; t < S_/64; t++) {
    const int cur = t & 1;
    __syncthreads();   // drains vmcnt: tile t ready; prev compute done -> buf cur^1 free
    if (t + 1 < S_/64) {
      const int k1 = (t + 1) * 64;
      #pragma unroll
      for (int i = 0; i < 2; i++) {
        const int row = i*32 + wave*8 + r8;
        gload_lds16(qk + (size_t)(b*S_ + k1 + row) * 2048 + 1024 + h*64 + ch*8, &Kt[cur^1][sbase + i*2048]);
        gload_lds16(vt + (size_t)(h*64 + row) * TOK + b*S_ + k1 + ch*8,         &Vt[cur^1][sbase + i*2048]);
      }
    }
    const short* Kc = &Kt[cur][0];
    const short* Vc = &Vt[cur][0];

    short8 kf[4][2], vf[4][2];
    #pragma unroll
    for (int kg = 0; kg < 4; kg++)
      #pragma unroll
      for (int kc = 0; kc < 2; kc++)
        kf[kg][kc] = *(const short8*)(Kc + (kg*16 + l15)*64 + ((l4 + kc*4) ^ l7) * 8);
    #pragma unroll
    for (int dg = 0; dg < 4; dg++)
      #pragma unroll
      for (int pc = 0; pc < 2; pc++)
        vf[dg][pc] = *(const short8*)(Vc + (dg*16 + l15)*64 + ((l4 + pc*4) ^ l7) * 8);
    float4_t mb[4];
    #pragma unroll
    for (int kg = 0; kg < 4; kg++)
      mb[kg] = *(const float4_t*)&maskb[b*S_ + t*64 + kg*16 + l4*4];

    #pragma unroll
    for (int mq = 0; mq < 2; mq++) {
      // S^T = K * Q^T : D[row=key=kg*16+l4*4+r][col=q=l15]
      float4_t sc[4];
      #pragma unroll
      for (int kg = 0; kg < 4; kg++) sc[kg] = (float4_t){0.f, 0.f, 0.f, 0.f};
      #pragma unroll
      for (int kg = 0; kg < 4; kg++)
        #pragma unroll
        for (int kc = 0; kc < 2; kc++)
          sc[kg] = __builtin_amdgcn_mfma_f32_16x16x32_bf16(kf[kg][kc], qa[mq][kc], sc[kg], 0, 0, 0);
      // scale to log2 domain + mask bias
      #pragma unroll
      for (int kg = 0; kg < 4; kg++)
        #pragma unroll
        for (int r = 0; r < 4; r++)
          sc[kg][r] = sc[kg][r] * SC2 + mb[kg][r];
      // row max: 15 in-register + 2 shuffles (over l4 groups)
      float pm = fmaxf(fmaxf(sc[0][0], sc[0][1]), fmaxf(sc[0][2], sc[0][3]));
      #pragma unroll
      for (int kg = 1; kg < 4; kg++)
        pm = fmaxf(pm, fmaxf(fmaxf(sc[kg][0], sc[kg][1]), fmaxf(sc[kg][2], sc[kg][3])));
      pm = fmaxf(pm, __shfl_xor(pm, 16));
      pm = fmaxf(pm, __shfl_xor(pm, 32));
      // defer-max: rescale only if max grew by > 8 (log2 units)
      if (__any(pm > m2[mq] + 8.0f)) {
        const float nm  = fmaxf(m2[mq], pm);
        const float esc = exp2f(m2[mq] - nm);
        m2[mq] = nm;
        lsum[mq] *= esc;
        #pragma unroll
        for (int r = 0; r < 4; r++) {
          const float er = __shfl(esc, l4*4 + r);
          #pragma unroll
          for (int dg = 0; dg < 4; dg++) acc[mq][dg][r] *= er;
        }
      }
      // P = 2^(s - m)
      #pragma unroll
      for (int kg = 0; kg < 4; kg++)
        #pragma unroll
        for (int r = 0; r < 4; r++)
          sc[kg][r] = exp2f(sc[kg][r] - m2[mq]);
      float ts = ((sc[0][0] + sc[0][1]) + (sc[0][2] + sc[0][3]))
               + ((sc[1][0] + sc[1][1]) + (sc[1][2] + sc[1][3]))
               + ((sc[2][0] + sc[2][1]) + (sc[2][2] + sc[2][3]))
               + ((sc[3][0] + sc[3][1]) + (sc[3][2] + sc[3][3]));
      ts += __shfl_xor(ts, 16);
      ts += __shfl_xor(ts, 32);
      lsum[mq] += ts;
      // P^T (regs) -> pbuf [q][k] bf16 pairs, u32-index swizzle ^ (l7<<2)
      const int prow = mq*16 + l15;
      #pragma unroll
      for (int kg = 0; kg < 4; kg++)
        #pragma unroll
        for (int pp = 0; pp < 2; pp++)
          pbu[wave][prow][(kg*8 + l4*2 + pp) ^ (l7 << 2)] = pack2bf(sc[kg][2*pp], sc[kg][2*pp + 1]);
      asm volatile("" ::: "memory");   // keep compiler from moving reads above writes
      short8 pf[2];
      #pragma unroll
      for (int pc = 0; pc < 2; pc++)
        pf[pc] = *(const short8*)&pbu[wave][prow][(l4*4 + pc*16) ^ (l7 << 2)];
      // O += P V : D[row=q][col=d]
      #pragma unroll
      for (int dg = 0; dg < 4; dg++)
        #pragma unroll
        for (int pc = 0; pc < 2; pc++)
          acc[mq][dg] = __builtin_amdgcn_mfma_f32_16x16x32_bf16(pf[pc], vf[dg][pc], acc[mq][dg], 0, 0, 0);
    }
  }

  // epilogue: divide by lsum (held at lanes 0..15 per q) and store
  #pragma unroll
  for (int mq = 0; mq < 2; mq++) {
    float linv[4];
    #pragma unroll
    for (int r = 0; r < 4; r++) linv[r] = 1.0f / __shfl(lsum[mq], l4*4 + r);
    #pragma unroll
    for (int dg = 0; dg < 4; dg++)
      #pragma unroll
      for (int r = 0; r < 4; r++)
        out[(size_t)(b*S_ + q0 + mq*16 + l4*4 + r) * D_ + h*64 + dg*16 + l15] =
            f2bf(acc[mq][dg][r] * linv[r]);
  }
}

// ---------------------------------------------------------------------------
extern "C" void kernel_launch(void* const* d_in, const int* in_sizes, int n_in,
                              void* d_out, int out_size, void* d_ws, size_t ws_size,
                              hipStream_t stream)
{
  const float* x     = (const float*)d_in[0];
  const int*   mask  = (const int*)d_in[1];
  const float* wq_w  = (const float*)d_in[2];
  const float* wq_b  = (const float*)d_in[3];
  const float* wk_w  = (const float*)d_in[4];
  const float* wk_b  = (const float*)d_in[5];
  const float* wv_w  = (const float*)d_in[6];
  const float* wv_b  = (const float*)d_in[7];
  const float* wo_w  = (const float*)d_in[8];
  const float* wo_b  = (const float*)d_in[9];
  const float* ff1_w = (const float*)d_in[10];
  const float* ff1_b = (const float*)d_in[11];
  const float* ff2_w = (const float*)d_in[12];
  const float* ff2_b = (const float*)d_in[13];
  const float* ln1_a = (const float*)d_in[14];
  const float* ln1_b = (const float*)d_in[15];
  const float* ln2_a = (const float*)d_in[16];
  const float* ln2_b = (const float*)d_in[17];

  uint8_t* ws = (uint8_t*)d_ws;
  const size_t MB = 1024 * 1024;
  short* wqk   = (short*)(ws + 0);        // (2048,1024) bf16: [wq; wk]      4 MB
  short* wvb   = (short*)(ws + 4*MB);     // (1024,1024)                     2 MB
  short* wob   = (short*)(ws + 6*MB);     // (1024,1024)                     2 MB
  short* ff1b  = (short*)(ws + 8*MB);     // (4096,1024)                     8 MB
  short* ff2b  = (short*)(ws + 16*MB);    // (1024,4096)                     8 MB
  float* bqk   = (float*)(ws + 24*MB);    // 2048 fp32 concat bias           8 KB
  float* maskb = (float*)(ws + 24*MB + 64*1024);  // TOK fp32               16 KB
  short* h1    = (short*)(ws + 25*MB);    // (4096,1024) bf16 (h1, later h2) 8 MB
  short* qkbuf = (short*)(ws + 33*MB);    // (4096,2048) bf16               16 MB
  short* vt    = (short*)(ws + 49*MB);    // (1024,4096) bf16                8 MB
  short* attno = (short*)(ws + 57*MB);    // (4096,1024) bf16                8 MB
  float* x2    = (float*)(ws + 65*MB);    // (4096,1024) fp32               16 MB
  short* ffa   = (short*)(ws + 33*MB);    // (4096,4096) bf16, reuses qkbuf/vt/attno (dead by then)

  // 1) weights -> bf16
  cvt_kernel<<<1024, 256, 0, stream>>>(wq_w, wqk,             1024*1024);
  cvt_kernel<<<1024, 256, 0, stream>>>(wk_w, wqk + 1024*1024, 1024*1024);
  cvt_kernel<<<1024, 256, 0, stream>>>(wv_w, wvb,             1024*1024);
  cvt_kernel<<<1024, 256, 0, stream>>>(wo_w, wob,             1024*1024);
  cvt_kernel<<<2048, 256, 0, stream>>>(ff1_w, ff1b,           4096*1024);
  cvt_kernel<<<2048, 256, 0, stream>>>(ff2_w, ff2b,           4096*1024);
  hipMemcpyAsync(bqk,        wq_b, 1024*sizeof(float), hipMemcpyDeviceToDevice, stream);
  hipMemcpyAsync(bqk + 1024, wk_b, 1024*sizeof(float), hipMemcpyDeviceToDevice, stream);
  maskb_kernel<<<TOK/256, 256, 0, stream>>>(mask, maskb, TOK);

  // 2) LN1: x -> h1 (bf16)
  ln_kernel<<<TOK, 256, 0, stream>>>(x, ln1_a, ln1_b, h1);

  // 3) [Q|K] = h1 @ [wq;wk]^T + b     (4096 x 2048)
  gemm_bt<0><<<dim3(2048/128, TOK/128), 256, 0, stream>>>(h1, wqk, qkbuf, bqk, nullptr, TOK, 2048, 1024);

  // 4) V^T = wv @ h1^T + bv[row]      (1024 x 4096)
  gemm_bt<1><<<dim3(TOK/128, 1024/128), 256, 0, stream>>>(wvb, h1, vt, wv_b, nullptr, 1024, TOK, 1024);

  // 5) flash attention -> attno (bf16)
  attn_kernel<<<dim3(S_/128, H_, B_), 256, 0, stream>>>(qkbuf, vt, maskb, attno);

  // 6) x2 = x + attno @ wo^T + bo     (fp32)
  gemm_bt<3><<<dim3(1024/128, TOK/128), 256, 0, stream>>>(attno, wob, x2, wo_b, x, TOK, 1024, 1024);

  // 7) LN2: x2 -> h2 (reuse h1 buffer)
  ln_kernel<<<TOK, 256, 0, stream>>>(x2, ln2_a, ln2_b, h1);

  // 8) ffa = relu(h2 @ ff1^T + b1)    (4096 x 4096 bf16)
  gemm_bt<2><<<dim3(FF_/128, TOK/128), 256, 0, stream>>>(h1, ff1b, ffa, ff1_b, nullptr, TOK, FF_, 1024);

  // 9) out = x2 + ffa @ ff2^T + b2    (4096 x 1024 fp32)
  gemm_bt<3><<<dim3(1024/128, TOK/128), 256, 0, stream>>>(ffa, ff2b, (float*)d_out, ff2_b, x2, TOK, 1024, FF_);
}

// Round 3
// 328.610 us; speedup vs baseline: 1.5199x; 1.1184x over previous
//
#include <hip/hip_runtime.h>
#include <hip/hip_bf16.h>
#include <stdint.h>

// Problem constants (B=2, S=2048, D=1024, H=16, DK=64, FF=4096)
#define B_   2
#define S_   2048
#define D_   1024
#define H_   16
#define FF_  4096
#define TOK  4096        // B*S
#define EPS_ 1e-5f

typedef __attribute__((ext_vector_type(8))) short short8;
typedef __attribute__((ext_vector_type(4))) short short4_t;
typedef __attribute__((ext_vector_type(4))) float float4_t;

__device__ __forceinline__ short f2bf(float f) {
  union { float f; uint32_t u; } v; v.f = f;
  uint32_t r = v.u + 0x7fffu + ((v.u >> 16) & 1u);
  return (short)(r >> 16);
}

// packed f32x2 -> bf16x2 (compiler emits v_cvt_pk_bf16_f32; RNE)
__device__ __forceinline__ uint32_t pkbf(float a, float b) {
  __hip_bfloat162 h = __float22bfloat162_rn(make_float2(a, b));   // x=low=a
  union { __hip_bfloat162 h; uint32_t u; } c; c.h = h; return c.u;
}

__device__ __forceinline__ void gload_lds16(const void* g, void* l) {
  __builtin_amdgcn_global_load_lds(
      (const __attribute__((address_space(1))) void*)g,
      (__attribute__((address_space(3))) void*)l, 16, 0, 0);
}

// ---------------- fp32 -> bf16 conversion (grid-stride, vectorized) --------
__global__ void cvt_kernel(const float* __restrict__ in, short* __restrict__ out, int n) {
  int idx = blockIdx.x * blockDim.x + threadIdx.x;
  int stride = gridDim.x * blockDim.x;
  for (int j = idx * 4; j < n; j += stride * 4) {
    float4_t v = *(const float4_t*)(in + j);
    short4_t o = { f2bf(v[0]), f2bf(v[1]), f2bf(v[2]), f2bf(v[3]) };
    *(short4_t*)(out + j) = o;
  }
}

// ---------------- mask -> additive bias ------------------------------------
__global__ void maskb_kernel(const int* __restrict__ m, float* __restrict__ o, int n) {
  int i = blockIdx.x * blockDim.x + threadIdx.x;
  if (i < n) o[i] = m[i] ? 0.0f : -1e30f;
}

// ---------------- LayerNorm (ddof=1, divide by std+eps), f32 in, bf16 out --
__global__ __launch_bounds__(256) void ln_kernel(
    const float* __restrict__ x, const float* __restrict__ alpha,
    const float* __restrict__ beta, short* __restrict__ out)
{
  const int row = blockIdx.x;
  const int tid = threadIdx.x;
  const float4_t v = *(const float4_t*)(x + (size_t)row * D_ + tid * 4);
  float s  = v[0] + v[1] + v[2] + v[3];
  float ss = v[0]*v[0] + v[1]*v[1] + v[2]*v[2] + v[3]*v[3];
  #pragma unroll
  for (int m = 1; m < 64; m <<= 1) { s += __shfl_xor(s, m); ss += __shfl_xor(ss, m); }
  __shared__ float red[8];
  const int wave = tid >> 6, lane = tid & 63;
  if (lane == 0) { red[wave] = s; red[4 + wave] = ss; }
  __syncthreads();
  s  = red[0] + red[1] + red[2] + red[3];
  ss = red[4] + red[5] + red[6] + red[7];
  const float mean = s * (1.0f / D_);
  float var = (ss - (float)D_ * mean * mean) * (1.0f / (D_ - 1));
  var = fmaxf(var, 0.0f);
  const float inv = 1.0f / (sqrtf(var) + EPS_);
  short4_t o;
  #pragma unroll
  for (int j = 0; j < 4; j++) {
    float a = alpha[tid*4 + j], bb = beta[tid*4 + j];
    o[j] = f2bf((v[j] - mean) * inv * a + bb);
  }
  *(short4_t*)(out + (size_t)row * D_ + tid * 4) = o;
}

// ---------------- GEMM: C(MxN) = A(MxK) * B(NxK)^T, bf16 in ----------------
// EPI 0: +bias[col] -> bf16      EPI 1: +bias[row] -> bf16
// EPI 2: relu(+bias[col]) -> bf16  EPI 3: res + C + bias[col] -> fp32
// BN in {64,128}: BN=64 doubles grid for shapes that land at 1 block/CU.
template<int EPI, int BN>
__global__ __launch_bounds__(256) void gemm_bt(
    const short* __restrict__ A, const short* __restrict__ Bm,
    void* __restrict__ Cout, const float* __restrict__ bias,
    const float* __restrict__ res, int M, int N, int K)
{
  __shared__ __align__(16) short As[128][32];
  __shared__ __align__(16) short Bs[BN][32];

  const int tid  = threadIdx.x;
  const int wave = tid >> 6, lane = tid & 63;
  const int l15  = lane & 15, l4 = lane >> 4;

  // XCD-aware bijective swizzle (nwg % 8 == 0 for all our launches)
  const int gx = gridDim.x;
  int bid = blockIdx.y * gx + blockIdx.x;
  const int q8 = (gx * gridDim.y) >> 3;
  bid = (bid & 7) * q8 + (bid >> 3);
  const int m0 = (bid / gx) * 128, n0 = (bid % gx) * BN;

  constexpr int MI = (BN == 128) ? 4 : 2;
  const int rb = (BN == 128) ? (wave >> 1) * 64 : wave * 32;   // wave row base
  const int cb = (BN == 128) ? (wave & 1) * 64 : 0;            // wave col base

  float4_t acc[MI][4] = {};

  const int scol = (lane & 3) * 8;
  const short* gA0 = A + (size_t)(m0 + wave*32 + (lane >> 2)) * K + scol;
  const short* gA1 = gA0 + (size_t)16 * K;
  const short* gB0;
  const short* gB1 = nullptr;
  if (BN == 128) {
    gB0 = Bm + (size_t)(n0 + wave*32 + (lane >> 2)) * K + scol;
    gB1 = gB0 + (size_t)16 * K;
  } else {
    gB0 = Bm + (size_t)(n0 + wave*16 + (lane >> 2)) * K + scol;
  }

  for (int k0 = 0; k0 < K; k0 += 32) {
    gload_lds16(gA0 + k0, &As[wave*32][0]);
    gload_lds16(gA1 + k0, &As[wave*32 + 16][0]);
    if (BN == 128) {
      gload_lds16(gB0 + k0, &Bs[wave*32][0]);
      gload_lds16(gB1 + k0, &Bs[wave*32 + 16][0]);
    } else {
      gload_lds16(gB0 + k0, &Bs[wave*16][0]);
    }
    __syncthreads();

    short8 af[MI], bf[4];
    #pragma unroll
    for (int i = 0; i < MI; i++)
      af[i] = *(const short8*)&As[rb + i*16 + l15][l4*8];
    #pragma unroll
    for (int i = 0; i < 4; i++)
      bf[i] = *(const short8*)&Bs[cb + i*16 + l15][l4*8];
    #pragma unroll
    for (int mi = 0; mi < MI; mi++)
      #pragma unroll
      for (int ni = 0; ni < 4; ni++)
        acc[mi][ni] = __builtin_amdgcn_mfma_f32_16x16x32_bf16(af[mi], bf[ni], acc[mi][ni], 0, 0, 0);
    __syncthreads();
  }

  const int crow0 = m0 + rb + l4*4;
  const int ccol0 = n0 + cb + l15;
  #pragma unroll
  for (int mi = 0; mi < MI; mi++) {
    #pragma unroll
    for (int ni = 0; ni < 4; ni++) {
      const int col = ccol0 + ni*16;
      const float bc = (EPI == 1) ? 0.0f : bias[col];
      #pragma unroll
      for (int r = 0; r < 4; r++) {
        const int row = crow0 + mi*16 + r;
        const float v = acc[mi][ni][r];
        if (EPI == 0) {
          ((short*)Cout)[(size_t)row * N + col] = f2bf(v + bc);
        } else if (EPI == 1) {
          ((short*)Cout)[(size_t)row * N + col] = f2bf(v + bias[row]);
        } else if (EPI == 2) {
          ((short*)Cout)[(size_t)row * N + col] = f2bf(fmaxf(v + bc, 0.0f));
        } else {
          ((float*)Cout)[(size_t)row * N + col] = res[(size_t)row * N + col] + v + bc;
        }
      }
    }
  }
}

// ---------------- Flash attention (swapped QK^T, P fully in-register) ------
// qk: (TOK x 2048) bf16, Q cols [0,1024), K cols [1024,2048)  (col = h*64+d)
// vt: (1024 x TOK) bf16. maskb: (TOK) fp32 additive bias.
// Trick: kf rows are loaded via permutation rho(kg,i) = 32*(kg>>1)+8*(i>>2)+
// 4*(kg&1)+(i&3), so after QK^T each lane holds keys [pc*32+8*l4, +8) --
// exactly PV's A-fragment slots. P needs no LDS and no cross-lane moves.
#define SC2 0.18033688f   // (1/8) * log2(e)

__global__ __launch_bounds__(256, 3) void attn_kernel(
    const short* __restrict__ qk, const short* __restrict__ vt,
    const float* __restrict__ maskb, short* __restrict__ out)
{
  // XCD swizzle over linear block id (nwg = 512)
  int bid = (blockIdx.z * H_ + blockIdx.y) * (S_/128) + blockIdx.x;
  bid = (bid & 7) * ((B_ * H_ * (S_/128)) >> 3) + (bid >> 3);
  const int qt = bid % (S_/128);
  const int h  = (bid / (S_/128)) % H_;
  const int b  = bid / ((S_/128) * H_);

  const int tid = threadIdx.x, wave = tid >> 6, lane = tid & 63;
  const int l15 = lane & 15, l4 = lane >> 4, l7 = l15 & 7;
  const int q0 = qt * 128 + wave * 32;

  // K tile [64 keys][64 dk], V^T tile [64 d][64 keys], XOR-swizzled chunks.
  __shared__ __align__(16) short Kt[2][4096];
  __shared__ __align__(16) short Vt[2][4096];

  short8 qa[2][2];
  #pragma unroll
  for (int mq = 0; mq < 2; mq++)
    #pragma unroll
    for (int kc = 0; kc < 2; kc++)
      qa[mq][kc] = *(const short8*)&qk[(size_t)(b*S_ + q0 + mq*16 + l15) * 2048 + h*64 + kc*32 + l4*8];

  float4_t acc[2][4];
  #pragma unroll
  for (int mq = 0; mq < 2; mq++)
    #pragma unroll
    for (int dg = 0; dg < 4; dg++)
      acc[mq][dg] = (float4_t){0.f, 0.f, 0.f, 0.f};
  float m2[2]   = {-1e30f, -1e30f};
  float lsum[2] = {0.f, 0.f};

  // staging: slot = i*256 + wave*64 + lane -> row = slot>>3, chunk = lane&7
  const int r8 = lane >> 3;
  const int ch = (lane & 7) ^ r8;
  const int sbase = wave * 512;

  #pragma unroll
  for (int i = 0; i < 2; i++) {
    const int row = i*32 + wave*8 + r8;
    gload_lds16(qk + (size_t)(b*S_ + row) * 2048 + 1024 + h*64 + ch*8, &Kt[0][sbase + i*2048]);
    gload_lds16(vt + (size_t)(h*64 + row) * TOK + b*S_ + ch*8,         &Vt[0][sbase + i*2048]);
  }

  // kf row permutation (per kg): row = 32*(kg>>1) + 8*(l15>>2) + 4*(kg&1) + (l15&3)
  int krow[4];
  #pragma unroll
  for (int kg = 0; kg < 4; kg++)
    krow[kg] = 32*(kg>>1) + 8*(l15>>2) + 4*(kg&1) + (l15&3);

  for (int t = 0; t < S_/64; t++) {
    const int cur = t & 1;
    __syncthreads();   // drains vmcnt: tile t ready; prev compute done
    if (t + 1 < S_/64) {
      const int k1 = (t + 1) * 64;
      #pragma unroll
      for (int i = 0; i < 2; i++) {
        const int row = i*32 + wave*8 + r8;
        gload_lds16(qk + (size_t)(b*S_ + k1 + row) * 2048 + 1024 + h*64 + ch*8, &Kt[cur^1][sbase + i*2048]);
        gload_lds16(vt + (size_t)(h*64 + row) * TOK + b*S_ + k1 + ch*8,         &Vt[cur^1][sbase + i*2048]);
      }
    }
    const short* Kc = &Kt[cur][0];
    const short* Vc = &Vt[cur][0];

    short8 kf[4][2], vf[4][2];
    #pragma unroll
    for (int kg = 0; kg < 4; kg++)
      #pragma unroll
      for (int kc = 0; kc < 2; kc++)
        kf[kg][kc] = *(const short8*)(Kc + krow[kg]*64 + ((l4 + kc*4) ^ (krow[kg] & 7)) * 8);
    #pragma unroll
    for (int dg = 0; dg < 4; dg++)
      #pragma unroll
      for (int pc = 0; pc < 2; pc++)
        vf[dg][pc] = *(const short8*)(Vc + (dg*16 + l15)*64 + ((l4 + pc*4) ^ l7) * 8);

    // mask bias at permuted keys: key(kg,r) = 32*(kg>>1) + 8*l4 + 4*(kg&1) + r
    float4_t mb[4];
    #pragma unroll
    for (int kg = 0; kg < 4; kg++)
      mb[kg] = *(const float4_t*)&maskb[b*S_ + t*64 + 32*(kg>>1) + 4*(kg&1) + 8*l4];

    #pragma unroll
    for (int mq = 0; mq < 2; mq++) {
      float4_t sc[4];
      #pragma unroll
      for (int kg = 0; kg < 4; kg++) sc[kg] = (float4_t){0.f, 0.f, 0.f, 0.f};
      __builtin_amdgcn_s_setprio(1);
      #pragma unroll
      for (int kg = 0; kg < 4; kg++)
        #pragma unroll
        for (int kc = 0; kc < 2; kc++)
          sc[kg] = __builtin_amdgcn_mfma_f32_16x16x32_bf16(kf[kg][kc], qa[mq][kc], sc[kg], 0, 0, 0);
      __builtin_amdgcn_s_setprio(0);
      #pragma unroll
      for (int kg = 0; kg < 4; kg++)
        #pragma unroll
        for (int r = 0; r < 4; r++)
          sc[kg][r] = sc[kg][r] * SC2 + mb[kg][r];
      // row max: in-register tree + 2 shuffles across l4 groups
      float pm = fmaxf(fmaxf(sc[0][0], sc[0][1]), fmaxf(sc[0][2], sc[0][3]));
      #pragma unroll
      for (int kg = 1; kg < 4; kg++)
        pm = fmaxf(pm, fmaxf(fmaxf(sc[kg][0], sc[kg][1]), fmaxf(sc[kg][2], sc[kg][3])));
      pm = fmaxf(pm, __shfl_xor(pm, 16));
      pm = fmaxf(pm, __shfl_xor(pm, 32));
      // defer-max (THR=8 in log2 units)
      if (__any(pm > m2[mq] + 8.0f)) {
        const float nm  = fmaxf(m2[mq], pm);
        const float esc = exp2f(m2[mq] - nm);
        m2[mq] = nm;
        lsum[mq] *= esc;
        #pragma unroll
        for (int r = 0; r < 4; r++) {
          const float er = __shfl(esc, l4*4 + r);
          #pragma unroll
          for (int dg = 0; dg < 4; dg++) acc[mq][dg][r] *= er;
        }
      }
      #pragma unroll
      for (int kg = 0; kg < 4; kg++)
        #pragma unroll
        for (int r = 0; r < 4; r++)
          sc[kg][r] = exp2f(sc[kg][r] - m2[mq]);
      float ts = ((sc[0][0] + sc[0][1]) + (sc[0][2] + sc[0][3]))
               + ((sc[1][0] + sc[1][1]) + (sc[1][2] + sc[1][3]))
               + ((sc[2][0] + sc[2][1]) + (sc[2][2] + sc[2][3]))
               + ((sc[3][0] + sc[3][1]) + (sc[3][2] + sc[3][3]));
      ts += __shfl_xor(ts, 16);
      ts += __shfl_xor(ts, 32);
      lsum[mq] += ts;
      // P -> bf16 A-fragments, fully in-register (keys already slot-ordered)
      union { short8 s8; uint32_t u[4]; } pu[2];
      #pragma unroll
      for (int pc = 0; pc < 2; pc++) {
        pu[pc].u[0] = pkbf(sc[2*pc][0],   sc[2*pc][1]);
        pu[pc].u[1] = pkbf(sc[2*pc][2],   sc[2*pc][3]);
        pu[pc].u[2] = pkbf(sc[2*pc+1][0], sc[2*pc+1][1]);
        pu[pc].u[3] = pkbf(sc[2*pc+1][2], sc[2*pc+1][3]);
      }
      __builtin_amdgcn_s_setprio(1);
      #pragma unroll
      for (int dg = 0; dg < 4; dg++)
        #pragma unroll
        for (int pc = 0; pc < 2; pc++)
          acc[mq][dg] = __builtin_amdgcn_mfma_f32_16x16x32_bf16(pu[pc].s8, vf[dg][pc], acc[mq][dg], 0, 0, 0);
      __builtin_amdgcn_s_setprio(0);
    }
  }

  #pragma unroll
  for (int mq = 0; mq < 2; mq++) {
    float linv[4];
    #pragma unroll
    for (int r = 0; r < 4; r++) linv[r] = 1.0f / __shfl(lsum[mq], l4*4 + r);
    #pragma unroll
    for (int dg = 0; dg < 4; dg++)
      #pragma unroll
      for (int r = 0; r < 4; r++)
        out[(size_t)(b*S_ + q0 + mq*16 + l4*4 + r) * D_ + h*64 + dg*16 + l15] =
            f2bf(acc[mq][dg][r] * linv[r]);
  }
}

// ---------------------------------------------------------------------------
extern "C" void kernel_launch(void* const* d_in, const int* in_sizes, int n_in,
                              void* d_out, int out_size, void* d_ws, size_t ws_size,
                              hipStream_t stream)
{
  const float* x     = (const float*)d_in[0];
  const int*   mask  = (const int*)d_in[1];
  const float* wq_w  = (const float*)d_in[2];
  const float* wq_b  = (const float*)d_in[3];
  const float* wk_w  = (const float*)d_in[4];
  const float* wk_b  = (const float*)d_in[5];
  const float* wv_w  = (const float*)d_in[6];
  const float* wv_b  = (const float*)d_in[7];
  const float* wo_w  = (const float*)d_in[8];
  const float* wo_b  = (const float*)d_in[9];
  const float* ff1_w = (const float*)d_in[10];
  const float* ff1_b = (const float*)d_in[11];
  const float* ff2_w = (const float*)d_in[12];
  const float* ff2_b = (const float*)d_in[13];
  const float* ln1_a = (const float*)d_in[14];
  const float* ln1_b = (const float*)d_in[15];
  const float* ln2_a = (const float*)d_in[16];
  const float* ln2_b = (const float*)d_in[17];

  uint8_t* ws = (uint8_t*)d_ws;
  const size_t MB = 1024 * 1024;
  short* wqk   = (short*)(ws + 0);        // (2048,1024) bf16: [wq; wk]      4 MB
  short* wvb   = (short*)(ws + 4*MB);     // (1024,1024)                     2 MB
  short* wob   = (short*)(ws + 6*MB);     // (1024,1024)                     2 MB
  short* ff1b  = (short*)(ws + 8*MB);     // (4096,1024)                     8 MB
  short* ff2b  = (short*)(ws + 16*MB);    // (1024,4096)                     8 MB
  float* bqk   = (float*)(ws + 24*MB);    // 2048 fp32 concat bias           8 KB
  float* maskb = (float*)(ws + 24*MB + 64*1024);  // TOK fp32               16 KB
  short* h1    = (short*)(ws + 25*MB);    // (4096,1024) bf16 (h1, later h2) 8 MB
  short* qkbuf = (short*)(ws + 33*MB);    // (4096,2048) bf16               16 MB
  short* vt    = (short*)(ws + 49*MB);    // (1024,4096) bf16                8 MB
  short* attno = (short*)(ws + 57*MB);    // (4096,1024) bf16                8 MB
  float* x2    = (float*)(ws + 65*MB);    // (4096,1024) fp32               16 MB
  short* ffa   = (short*)(ws + 33*MB);    // (4096,4096) bf16 (reuses dead bufs)

  // 1) weights -> bf16
  cvt_kernel<<<1024, 256, 0, stream>>>(wq_w, wqk,             1024*1024);
  cvt_kernel<<<1024, 256, 0, stream>>>(wk_w, wqk + 1024*1024, 1024*1024);
  cvt_kernel<<<1024, 256, 0, stream>>>(wv_w, wvb,             1024*1024);
  cvt_kernel<<<1024, 256, 0, stream>>>(wo_w, wob,             1024*1024);
  cvt_kernel<<<2048, 256, 0, stream>>>(ff1_w, ff1b,           4096*1024);
  cvt_kernel<<<2048, 256, 0, stream>>>(ff2_w, ff2b,           4096*1024);
  hipMemcpyAsync(bqk,        wq_b, 1024*sizeof(float), hipMemcpyDeviceToDevice, stream);
  hipMemcpyAsync(bqk + 1024, wk_b, 1024*sizeof(float), hipMemcpyDeviceToDevice, stream);
  maskb_kernel<<<TOK/256, 256, 0, stream>>>(mask, maskb, TOK);

  // 2) LN1: x -> h1 (bf16)
  ln_kernel<<<TOK, 256, 0, stream>>>(x, ln1_a, ln1_b, h1);

  // 3) [Q|K] = h1 @ [wq;wk]^T + b     (4096 x 2048), 512 blocks
  gemm_bt<0,128><<<dim3(2048/128, TOK/128), 256, 0, stream>>>(h1, wqk, qkbuf, bqk, nullptr, TOK, 2048, 1024);

  // 4) V^T = wv @ h1^T + bv[row]      (1024 x 4096), BN=64 -> 512 blocks
  gemm_bt<1,64><<<dim3(TOK/64, 1024/128), 256, 0, stream>>>(wvb, h1, vt, wv_b, nullptr, 1024, TOK, 1024);

  // 5) flash attention -> attno (bf16)
  attn_kernel<<<dim3(S_/128, H_, B_), 256, 0, stream>>>(qkbuf, vt, maskb, attno);

  // 6) x2 = x + attno @ wo^T + bo     (fp32), BN=64 -> 512 blocks
  gemm_bt<3,64><<<dim3(1024/64, TOK/128), 256, 0, stream>>>(attno, wob, x2, wo_b, x, TOK, 1024, 1024);

  // 7) LN2: x2 -> h2 (reuse h1 buffer)
  ln_kernel<<<TOK, 256, 0, stream>>>(x2, ln2_a, ln2_b, h1);

  // 8) ffa = relu(h2 @ ff1^T + b1)    (4096 x 4096 bf16), 1024 blocks
  gemm_bt<2,128><<<dim3(FF_/128, TOK/128), 256, 0, stream>>>(h1, ff1b, ffa, ff1_b, nullptr, TOK, FF_, 1024);

  // 9) out = x2 + ffa @ ff2^T + b2    (4096 x 1024 fp32), BN=64 -> 512 blocks
  gemm_bt<3,64><<<dim3(1024/64, TOK/128), 256, 0, stream>>>(ffa, ff2b, (float*)d_out, ff2_b, x2, TOK, 1024, FF_);
}

// Round 4
// 314.637 us; speedup vs baseline: 1.5874x; 1.0444x over previous
//
#include <hip/hip_runtime.h>
#include <hip/hip_bf16.h>
#include <stdint.h>

// Problem constants (B=2, S=2048, D=1024, H=16, DK=64, FF=4096)
#define B_   2
#define S_   2048
#define D_   1024
#define H_   16
#define FF_  4096
#define TOK  4096        // B*S
#define EPS_ 1e-5f

typedef __attribute__((ext_vector_type(8))) short short8;
typedef __attribute__((ext_vector_type(4))) short short4_t;
typedef __attribute__((ext_vector_type(4))) float float4_t;

__device__ __forceinline__ short f2bf(float f) {
  union { float f; uint32_t u; } v; v.f = f;
  uint32_t r = v.u + 0x7fffu + ((v.u >> 16) & 1u);
  return (short)(r >> 16);
}

// packed f32x2 -> bf16x2 (compiler emits v_cvt_pk_bf16_f32; RNE)
__device__ __forceinline__ uint32_t pkbf(float a, float b) {
  __hip_bfloat162 h = __float22bfloat162_rn(make_float2(a, b));   // x=low=a
  union { __hip_bfloat162 h; uint32_t u; } c; c.h = h; return c.u;
}

__device__ __forceinline__ void gload_lds16(const void* g, void* l) {
  __builtin_amdgcn_global_load_lds(
      (const __attribute__((address_space(1))) void*)g,
      (__attribute__((address_space(3))) void*)l, 16, 0, 0);
}

// ---------------- fp32 -> bf16 conversion (grid-stride, vectorized) --------
__global__ void cvt_kernel(const float* __restrict__ in, short* __restrict__ out, int n) {
  int idx = blockIdx.x * blockDim.x + threadIdx.x;
  int stride = gridDim.x * blockDim.x;
  for (int j = idx * 4; j < n; j += stride * 4) {
    float4_t v = *(const float4_t*)(in + j);
    short4_t o = { f2bf(v[0]), f2bf(v[1]), f2bf(v[2]), f2bf(v[3]) };
    *(short4_t*)(out + j) = o;
  }
}

// ---------------- mask -> additive bias ------------------------------------
__global__ void maskb_kernel(const int* __restrict__ m, float* __restrict__ o, int n) {
  int i = blockIdx.x * blockDim.x + threadIdx.x;
  if (i < n) o[i] = m[i] ? 0.0f : -1e30f;
}

// ---------------- LayerNorm (ddof=1, divide by std+eps), f32 in, bf16 out --
__global__ __launch_bounds__(256) void ln_kernel(
    const float* __restrict__ x, const float* __restrict__ alpha,
    const float* __restrict__ beta, short* __restrict__ out)
{
  const int row = blockIdx.x;
  const int tid = threadIdx.x;
  const float4_t v = *(const float4_t*)(x + (size_t)row * D_ + tid * 4);
  float s  = v[0] + v[1] + v[2] + v[3];
  float ss = v[0]*v[0] + v[1]*v[1] + v[2]*v[2] + v[3]*v[3];
  #pragma unroll
  for (int m = 1; m < 64; m <<= 1) { s += __shfl_xor(s, m); ss += __shfl_xor(ss, m); }
  __shared__ float red[8];
  const int wave = tid >> 6, lane = tid & 63;
  if (lane == 0) { red[wave] = s; red[4 + wave] = ss; }
  __syncthreads();
  s  = red[0] + red[1] + red[2] + red[3];
  ss = red[4] + red[5] + red[6] + red[7];
  const float mean = s * (1.0f / D_);
  float var = (ss - (float)D_ * mean * mean) * (1.0f / (D_ - 1));
  var = fmaxf(var, 0.0f);
  const float inv = 1.0f / (sqrtf(var) + EPS_);
  short4_t o;
  #pragma unroll
  for (int j = 0; j < 4; j++) {
    float a = alpha[tid*4 + j], bb = beta[tid*4 + j];
    o[j] = f2bf((v[j] - mean) * inv * a + bb);
  }
  *(short4_t*)(out + (size_t)row * D_ + tid * 4) = o;
}

// ---------------- GEMM: C(MxN) = A(MxK) * B(NxK)^T, bf16 in ----------------
// EPI 0: +bias[col] -> bf16      EPI 1: +bias[row] -> bf16
// EPI 2: relu(+bias[col]) -> bf16  EPI 3: res + C + bias[col] -> fp32
template<int EPI, int BN>
__global__ __launch_bounds__(256) void gemm_bt(
    const short* __restrict__ A, const short* __restrict__ Bm,
    void* __restrict__ Cout, const float* __restrict__ bias,
    const float* __restrict__ res, int M, int N, int K)
{
  __shared__ __align__(16) short As[128][32];
  __shared__ __align__(16) short Bs[BN][32];

  const int tid  = threadIdx.x;
  const int wave = tid >> 6, lane = tid & 63;
  const int l15  = lane & 15, l4 = lane >> 4;

  // XCD-aware bijective swizzle (nwg % 8 == 0 for all our launches)
  const int gx = gridDim.x;
  int bid = blockIdx.y * gx + blockIdx.x;
  const int q8 = (gx * gridDim.y) >> 3;
  bid = (bid & 7) * q8 + (bid >> 3);
  const int m0 = (bid / gx) * 128, n0 = (bid % gx) * BN;

  constexpr int MI = (BN == 128) ? 4 : 2;
  const int rb = (BN == 128) ? (wave >> 1) * 64 : wave * 32;   // wave row base
  const int cb = (BN == 128) ? (wave & 1) * 64 : 0;            // wave col base

  float4_t acc[MI][4] = {};

  const int scol = (lane & 3) * 8;
  const short* gA0 = A + (size_t)(m0 + wave*32 + (lane >> 2)) * K + scol;
  const short* gA1 = gA0 + (size_t)16 * K;
  const short* gB0;
  const short* gB1 = nullptr;
  if (BN == 128) {
    gB0 = Bm + (size_t)(n0 + wave*32 + (lane >> 2)) * K + scol;
    gB1 = gB0 + (size_t)16 * K;
  } else {
    gB0 = Bm + (size_t)(n0 + wave*16 + (lane >> 2)) * K + scol;
  }

  for (int k0 = 0; k0 < K; k0 += 32) {
    gload_lds16(gA0 + k0, &As[wave*32][0]);
    gload_lds16(gA1 + k0, &As[wave*32 + 16][0]);
    if (BN == 128) {
      gload_lds16(gB0 + k0, &Bs[wave*32][0]);
      gload_lds16(gB1 + k0, &Bs[wave*32 + 16][0]);
    } else {
      gload_lds16(gB0 + k0, &Bs[wave*16][0]);
    }
    __syncthreads();

    short8 af[MI], bf[4];
    #pragma unroll
    for (int i = 0; i < MI; i++)
      af[i] = *(const short8*)&As[rb + i*16 + l15][l4*8];
    #pragma unroll
    for (int i = 0; i < 4; i++)
      bf[i] = *(const short8*)&Bs[cb + i*16 + l15][l4*8];
    #pragma unroll
    for (int mi = 0; mi < MI; mi++)
      #pragma unroll
      for (int ni = 0; ni < 4; ni++)
        acc[mi][ni] = __builtin_amdgcn_mfma_f32_16x16x32_bf16(af[mi], bf[ni], acc[mi][ni], 0, 0, 0);
    __syncthreads();
  }

  const int crow0 = m0 + rb + l4*4;
  const int ccol0 = n0 + cb + l15;
  #pragma unroll
  for (int mi = 0; mi < MI; mi++) {
    #pragma unroll
    for (int ni = 0; ni < 4; ni++) {
      const int col = ccol0 + ni*16;
      const float bc = (EPI == 1) ? 0.0f : bias[col];
      #pragma unroll
      for (int r = 0; r < 4; r++) {
        const int row = crow0 + mi*16 + r;
        const float v = acc[mi][ni][r];
        if (EPI == 0) {
          ((short*)Cout)[(size_t)row * N + col] = f2bf(v + bc);
        } else if (EPI == 1) {
          ((short*)Cout)[(size_t)row * N + col] = f2bf(v + bias[row]);
        } else if (EPI == 2) {
          ((short*)Cout)[(size_t)row * N + col] = f2bf(fmaxf(v + bc, 0.0f));
        } else {
          ((float*)Cout)[(size_t)row * N + col] = res[(size_t)row * N + col] + v + bc;
        }
      }
    }
  }
}

// ---------------- Flash attention (swapped QK^T, P fully in-register) ------
// qk: (TOK x 2048) bf16, Q cols [0,1024), K cols [1024,2048)  (col = h*64+d)
// vt: (1024 x TOK) bf16. maskb: (TOK) fp32 additive bias.
// 1024 blocks (64 q-rows each), 4 waves x 16 q-rows. KVBLK=64, double-buffered.
// kf row permutation rho(kg,i)=32*(kg>>1)+8*(i>>2)+4*(kg&1)+(i&3) puts P's
// keys exactly in PV A-fragment slot order: P stays in registers.
// LDS chunk swizzle g(row) = (row&3) | (bit3(row)<<2) -- balanced (8 lanes
// per 16B quad) for kf reads, vf reads, AND the linear staging write.
#define SC2 0.18033688f   // (1/8) * log2(e)

__global__ __launch_bounds__(256, 4) void attn_kernel(
    const short* __restrict__ qk, const short* __restrict__ vt,
    const float* __restrict__ maskb, short* __restrict__ out)
{
  // XCD swizzle over linear block id (nwg = 1024): contiguous work chunk/XCD
  int bid = (blockIdx.z * H_ + blockIdx.y) * (S_/64) + blockIdx.x;
  bid = (bid & 7) * ((B_ * H_ * (S_/64)) >> 3) + (bid >> 3);
  const int qt = bid % (S_/64);
  const int h  = (bid / (S_/64)) % H_;
  const int b  = bid / ((S_/64) * H_);

  const int tid = threadIdx.x, wave = tid >> 6, lane = tid & 63;
  const int l15 = lane & 15, l4 = lane >> 4;
  const int q0 = qt * 64 + wave * 16;

  // K tile [64 keys][64 dk], V^T tile [64 d][64 keys], g-swizzled chunks.
  __shared__ __align__(16) short Kt[2][4096];
  __shared__ __align__(16) short Vt[2][4096];

  short8 qa[2];
  #pragma unroll
  for (int kc = 0; kc < 2; kc++)
    qa[kc] = *(const short8*)&qk[(size_t)(b*S_ + q0 + l15) * 2048 + h*64 + kc*32 + l4*8];

  float4_t acc[4];
  #pragma unroll
  for (int dg = 0; dg < 4; dg++) acc[dg] = (float4_t){0.f, 0.f, 0.f, 0.f};
  float m2   = -1e30f;
  float lsum = 0.f;

  // staging: slot = i*256 + wave*64 + lane -> row = i*32 + wave*8 + (lane>>3)
  // source chunk = (lane&7) ^ g(row); g(row) = (r8&3) | ((wave&1)<<2)
  const int r8 = lane >> 3;
  const int ch = (lane & 7) ^ ((r8 & 3) | ((wave & 1) << 2));
  const int sbase = wave * 512;

  #pragma unroll
  for (int i = 0; i < 2; i++) {
    const int row = i*32 + wave*8 + r8;
    gload_lds16(qk + (size_t)(b*S_ + row) * 2048 + 1024 + h*64 + ch*8, &Kt[0][sbase + i*2048]);
    gload_lds16(vt + (size_t)(h*64 + row) * TOK + b*S_ + ch*8,         &Vt[0][sbase + i*2048]);
  }

  // kf rows: rho = 32*(kg>>1) + 8*(l15>>2) + 4*(kg&1) + (l15&3)
  // g(rho) = (l15&3) | (((l15>>2)&1)<<2)  -- kg-independent
  int krow[4];
  #pragma unroll
  for (int kg = 0; kg < 4; kg++)
    krow[kg] = 32*(kg>>1) + 8*(l15>>2) + 4*(kg&1) + (l15&3);
  const int gq = (l15 & 3) | (((l15 >> 2) & 1) << 2);
  const int gv = (l15 & 3) | (((l15 >> 3) & 1) << 2);   // for rows dg*16+l15

  for (int t = 0; t < S_/64; t++) {
    const int cur = t & 1;
    __syncthreads();   // drains vmcnt: tile t ready; prev compute done
    if (t + 1 < S_/64) {
      const int k1 = (t + 1) * 64;
      #pragma unroll
      for (int i = 0; i < 2; i++) {
        const int row = i*32 + wave*8 + r8;
        gload_lds16(qk + (size_t)(b*S_ + k1 + row) * 2048 + 1024 + h*64 + ch*8, &Kt[cur^1][sbase + i*2048]);
        gload_lds16(vt + (size_t)(h*64 + row) * TOK + b*S_ + k1 + ch*8,         &Vt[cur^1][sbase + i*2048]);
      }
    }
    const short* Kc = &Kt[cur][0];
    const short* Vc = &Vt[cur][0];

    short8 kf[4][2], vf[4][2];
    #pragma unroll
    for (int kg = 0; kg < 4; kg++)
      #pragma unroll
      for (int kc = 0; kc < 2; kc++)
        kf[kg][kc] = *(const short8*)(Kc + krow[kg]*64 + ((l4 + kc*4) ^ gq) * 8);
    #pragma unroll
    for (int dg = 0; dg < 4; dg++)
      #pragma unroll
      for (int pc = 0; pc < 2; pc++)
        vf[dg][pc] = *(const short8*)(Vc + (dg*16 + l15)*64 + ((l4 + pc*4) ^ gv) * 8);

    // mask bias at permuted keys: key(kg,r) = 32*(kg>>1) + 8*l4 + 4*(kg&1) + r
    float4_t mb[4];
    #pragma unroll
    for (int kg = 0; kg < 4; kg++)
      mb[kg] = *(const float4_t*)&maskb[b*S_ + t*64 + 32*(kg>>1) + 4*(kg&1) + 8*l4];

    float4_t sc[4];
    #pragma unroll
    for (int kg = 0; kg < 4; kg++) sc[kg] = (float4_t){0.f, 0.f, 0.f, 0.f};
    __builtin_amdgcn_s_setprio(1);
    #pragma unroll
    for (int kg = 0; kg < 4; kg++)
      #pragma unroll
      for (int kc = 0; kc < 2; kc++)
        sc[kg] = __builtin_amdgcn_mfma_f32_16x16x32_bf16(kf[kg][kc], qa[kc], sc[kg], 0, 0, 0);
    __builtin_amdgcn_s_setprio(0);
    #pragma unroll
    for (int kg = 0; kg < 4; kg++)
      #pragma unroll
      for (int r = 0; r < 4; r++)
        sc[kg][r] = sc[kg][r] * SC2 + mb[kg][r];
    // row max: in-register tree + 2 shuffles across l4 groups
    float pm = fmaxf(fmaxf(sc[0][0], sc[0][1]), fmaxf(sc[0][2], sc[0][3]));
    #pragma unroll
    for (int kg = 1; kg < 4; kg++)
      pm = fmaxf(pm, fmaxf(fmaxf(sc[kg][0], sc[kg][1]), fmaxf(sc[kg][2], sc[kg][3])));
    pm = fmaxf(pm, __shfl_xor(pm, 16));
    pm = fmaxf(pm, __shfl_xor(pm, 32));
    // defer-max (THR=8 in log2 units)
    if (__any(pm > m2 + 8.0f)) {
      const float nm  = fmaxf(m2, pm);
      const float esc = exp2f(m2 - nm);
      m2 = nm;
      lsum *= esc;
      #pragma unroll
      for (int r = 0; r < 4; r++) {
        const float er = __shfl(esc, l4*4 + r);
        #pragma unroll
        for (int dg = 0; dg < 4; dg++) acc[dg][r] *= er;
      }
    }
    #pragma unroll
    for (int kg = 0; kg < 4; kg++)
      #pragma unroll
      for (int r = 0; r < 4; r++)
        sc[kg][r] = exp2f(sc[kg][r] - m2);
    float ts = ((sc[0][0] + sc[0][1]) + (sc[0][2] + sc[0][3]))
             + ((sc[1][0] + sc[1][1]) + (sc[1][2] + sc[1][3]))
             + ((sc[2][0] + sc[2][1]) + (sc[2][2] + sc[2][3]))
             + ((sc[3][0] + sc[3][1]) + (sc[3][2] + sc[3][3]));
    ts += __shfl_xor(ts, 16);
    ts += __shfl_xor(ts, 32);
    lsum += ts;
    // P -> bf16 A-fragments, fully in-register (keys already slot-ordered)
    union { short8 s8; uint32_t u[4]; } pu[2];
    #pragma unroll
    for (int pc = 0; pc < 2; pc++) {
      pu[pc].u[0] = pkbf(sc[2*pc][0],   sc[2*pc][1]);
      pu[pc].u[1] = pkbf(sc[2*pc][2],   sc[2*pc][3]);
      pu[pc].u[2] = pkbf(sc[2*pc+1][0], sc[2*pc+1][1]);
      pu[pc].u[3] = pkbf(sc[2*pc+1][2], sc[2*pc+1][3]);
    }
    __builtin_amdgcn_s_setprio(1);
    #pragma unroll
    for (int dg = 0; dg < 4; dg++)
      #pragma unroll
      for (int pc = 0; pc < 2; pc++)
        acc[dg] = __builtin_amdgcn_mfma_f32_16x16x32_bf16(pu[pc].s8, vf[dg][pc], acc[dg], 0, 0, 0);
    __builtin_amdgcn_s_setprio(0);
  }

  float linv[4];
  #pragma unroll
  for (int r = 0; r < 4; r++) linv[r] = 1.0f / __shfl(lsum, l4*4 + r);
  #pragma unroll
  for (int dg = 0; dg < 4; dg++)
    #pragma unroll
    for (int r = 0; r < 4; r++)
      out[(size_t)(b*S_ + q0 + l4*4 + r) * D_ + h*64 + dg*16 + l15] =
          f2bf(acc[dg][r] * linv[r]);
}

// ---------------------------------------------------------------------------
extern "C" void kernel_launch(void* const* d_in, const int* in_sizes, int n_in,
                              void* d_out, int out_size, void* d_ws, size_t ws_size,
                              hipStream_t stream)
{
  const float* x     = (const float*)d_in[0];
  const int*   mask  = (const int*)d_in[1];
  const float* wq_w  = (const float*)d_in[2];
  const float* wq_b  = (const float*)d_in[3];
  const float* wk_w  = (const float*)d_in[4];
  const float* wk_b  = (const float*)d_in[5];
  const float* wv_w  = (const float*)d_in[6];
  const float* wv_b  = (const float*)d_in[7];
  const float* wo_w  = (const float*)d_in[8];
  const float* wo_b  = (const float*)d_in[9];
  const float* ff1_w = (const float*)d_in[10];
  const float* ff1_b = (const float*)d_in[11];
  const float* ff2_w = (const float*)d_in[12];
  const float* ff2_b = (const float*)d_in[13];
  const float* ln1_a = (const float*)d_in[14];
  const float* ln1_b = (const float*)d_in[15];
  const float* ln2_a = (const float*)d_in[16];
  const float* ln2_b = (const float*)d_in[17];

  uint8_t* ws = (uint8_t*)d_ws;
  const size_t MB = 1024 * 1024;
  short* wqk   = (short*)(ws + 0);        // (2048,1024) bf16: [wq; wk]      4 MB
  short* wvb   = (short*)(ws + 4*MB);     // (1024,1024)                     2 MB
  short* wob   = (short*)(ws + 6*MB);     // (1024,1024)                     2 MB
  short* ff1b  = (short*)(ws + 8*MB);     // (4096,1024)                     8 MB
  short* ff2b  = (short*)(ws + 16*MB);    // (1024,4096)                     8 MB
  float* bqk   = (float*)(ws + 24*MB);    // 2048 fp32 concat bias           8 KB
  float* maskb = (float*)(ws + 24*MB + 64*1024);  // TOK fp32               16 KB
  short* h1    = (short*)(ws + 25*MB);    // (4096,1024) bf16 (h1, later h2) 8 MB
  short* qkbuf = (short*)(ws + 33*MB);    // (4096,2048) bf16               16 MB
  short* vt    = (short*)(ws + 49*MB);    // (1024,4096) bf16                8 MB
  short* attno = (short*)(ws + 57*MB);    // (4096,1024) bf16                8 MB
  float* x2    = (float*)(ws + 65*MB);    // (4096,1024) fp32               16 MB
  short* ffa   = (short*)(ws + 33*MB);    // (4096,4096) bf16 (reuses dead bufs)

  // 1) weights -> bf16
  cvt_kernel<<<1024, 256, 0, stream>>>(wq_w, wqk,             1024*1024);
  cvt_kernel<<<1024, 256, 0, stream>>>(wk_w, wqk + 1024*1024, 1024*1024);
  cvt_kernel<<<1024, 256, 0, stream>>>(wv_w, wvb,             1024*1024);
  cvt_kernel<<<1024, 256, 0, stream>>>(wo_w, wob,             1024*1024);
  cvt_kernel<<<2048, 256, 0, stream>>>(ff1_w, ff1b,           4096*1024);
  cvt_kernel<<<2048, 256, 0, stream>>>(ff2_w, ff2b,           4096*1024);
  hipMemcpyAsync(bqk,        wq_b, 1024*sizeof(float), hipMemcpyDeviceToDevice, stream);
  hipMemcpyAsync(bqk + 1024, wk_b, 1024*sizeof(float), hipMemcpyDeviceToDevice, stream);
  maskb_kernel<<<TOK/256, 256, 0, stream>>>(mask, maskb, TOK);

  // 2) LN1: x -> h1 (bf16)
  ln_kernel<<<TOK, 256, 0, stream>>>(x, ln1_a, ln1_b, h1);

  // 3) [Q|K] = h1 @ [wq;wk]^T + b     (4096 x 2048), 512 blocks
  gemm_bt<0,128><<<dim3(2048/128, TOK/128), 256, 0, stream>>>(h1, wqk, qkbuf, bqk, nullptr, TOK, 2048, 1024);

  // 4) V^T = wv @ h1^T + bv[row]      (1024 x 4096), BN=64 -> 512 blocks
  gemm_bt<1,64><<<dim3(TOK/64, 1024/128), 256, 0, stream>>>(wvb, h1, vt, wv_b, nullptr, 1024, TOK, 1024);

  // 5) flash attention -> attno (bf16), 1024 blocks
  attn_kernel<<<dim3(S_/64, H_, B_), 256, 0, stream>>>(qkbuf, vt, maskb, attno);

  // 6) x2 = x + attno @ wo^T + bo     (fp32), BN=64 -> 512 blocks
  gemm_bt<3,64><<<dim3(1024/64, TOK/128), 256, 0, stream>>>(attno, wob, x2, wo_b, x, TOK, 1024, 1024);

  // 7) LN2: x2 -> h2 (reuse h1 buffer)
  ln_kernel<<<TOK, 256, 0, stream>>>(x2, ln2_a, ln2_b, h1);

  // 8) ffa = relu(h2 @ ff1^T + b1)    (4096 x 4096 bf16), 1024 blocks
  gemm_bt<2,128><<<dim3(FF_/128, TOK/128), 256, 0, stream>>>(h1, ff1b, ffa, ff1_b, nullptr, TOK, FF_, 1024);

  // 9) out = x2 + ffa @ ff2^T + b2    (4096 x 1024 fp32), BN=64 -> 512 blocks
  gemm_bt<3,64><<<dim3(1024/64, TOK/128), 256, 0, stream>>>(ffa, ff2b, (float*)d_out, ff2_b, x2, TOK, 1024, FF_);
}

// Round 5
// 309.241 us; speedup vs baseline: 1.6151x; 1.0175x over previous
//
#include <hip/hip_runtime.h>
#include <hip/hip_bf16.h>
#include <stdint.h>

// Problem constants (B=2, S=2048, D=1024, H=16, DK=64, FF=4096)
#define B_   2
#define S_   2048
#define D_   1024
#define H_   16
#define FF_  4096
#define TOK  4096        // B*S
#define EPS_ 1e-5f

typedef __attribute__((ext_vector_type(8))) short short8;
typedef __attribute__((ext_vector_type(4))) short short4_t;
typedef __attribute__((ext_vector_type(4))) float float4_t;

__device__ __forceinline__ short f2bf(float f) {
  union { float f; uint32_t u; } v; v.f = f;
  uint32_t r = v.u + 0x7fffu + ((v.u >> 16) & 1u);
  return (short)(r >> 16);
}

// packed f32x2 -> bf16x2 (compiler emits v_cvt_pk_bf16_f32; RNE)
__device__ __forceinline__ uint32_t pkbf(float a, float b) {
  __hip_bfloat162 h = __float22bfloat162_rn(make_float2(a, b));   // x=low=a
  union { __hip_bfloat162 h; uint32_t u; } c; c.h = h; return c.u;
}

__device__ __forceinline__ void gload_lds16(const void* g, void* l) {
  __builtin_amdgcn_global_load_lds(
      (const __attribute__((address_space(1))) void*)g,
      (__attribute__((address_space(3))) void*)l, 16, 0, 0);
}

// ---------------- fp32 -> bf16 conversion (grid-stride, vectorized) --------
__global__ void cvt_kernel(const float* __restrict__ in, short* __restrict__ out, int n) {
  int idx = blockIdx.x * blockDim.x + threadIdx.x;
  int stride = gridDim.x * blockDim.x;
  for (int j = idx * 4; j < n; j += stride * 4) {
    float4_t v = *(const float4_t*)(in + j);
    short4_t o = { f2bf(v[0]), f2bf(v[1]), f2bf(v[2]), f2bf(v[3]) };
    *(short4_t*)(out + j) = o;
  }
}

// ---------------- mask -> additive bias ------------------------------------
__global__ void maskb_kernel(const int* __restrict__ m, float* __restrict__ o, int n) {
  int i = blockIdx.x * blockDim.x + threadIdx.x;
  if (i < n) o[i] = m[i] ? 0.0f : -1e30f;
}

// ---------------- split-K combine: out = x2 + bias + p0 + out --------------
__global__ void combine_kernel(const float* __restrict__ x2, const float* __restrict__ p0,
                               float* __restrict__ out, const float* __restrict__ bias, int n) {
  int idx = blockIdx.x * blockDim.x + threadIdx.x;
  int stride = gridDim.x * blockDim.x;
  for (int j = idx * 4; j < n; j += stride * 4) {
    float4_t a = *(const float4_t*)(x2 + j);
    float4_t b = *(const float4_t*)(p0 + j);
    float4_t c = *(const float4_t*)(out + j);
    float4_t bb = *(const float4_t*)(bias + (j & (D_ - 1)));
    float4_t o = { a[0]+b[0]+c[0]+bb[0], a[1]+b[1]+c[1]+bb[1],
                   a[2]+b[2]+c[2]+bb[2], a[3]+b[3]+c[3]+bb[3] };
    *(float4_t*)(out + j) = o;
  }
}

// ---------------- LayerNorm (ddof=1, divide by std+eps), f32 in, bf16 out --
__global__ __launch_bounds__(256) void ln_kernel(
    const float* __restrict__ x, const float* __restrict__ alpha,
    const float* __restrict__ beta, short* __restrict__ out)
{
  const int row = blockIdx.x;
  const int tid = threadIdx.x;
  const float4_t v = *(const float4_t*)(x + (size_t)row * D_ + tid * 4);
  float s  = v[0] + v[1] + v[2] + v[3];
  float ss = v[0]*v[0] + v[1]*v[1] + v[2]*v[2] + v[3]*v[3];
  #pragma unroll
  for (int m = 1; m < 64; m <<= 1) { s += __shfl_xor(s, m); ss += __shfl_xor(ss, m); }
  __shared__ float red[8];
  const int wave = tid >> 6, lane = tid & 63;
  if (lane == 0) { red[wave] = s; red[4 + wave] = ss; }
  __syncthreads();
  s  = red[0] + red[1] + red[2] + red[3];
  ss = red[4] + red[5] + red[6] + red[7];
  const float mean = s * (1.0f / D_);
  float var = (ss - (float)D_ * mean * mean) * (1.0f / (D_ - 1));
  var = fmaxf(var, 0.0f);
  const float inv = 1.0f / (sqrtf(var) + EPS_);
  short4_t o;
  #pragma unroll
  for (int j = 0; j < 4; j++) {
    float a = alpha[tid*4 + j], bb = beta[tid*4 + j];
    o[j] = f2bf((v[j] - mean) * inv * a + bb);
  }
  *(short4_t*)(out + (size_t)row * D_ + tid * 4) = o;
}

// ---------------- GEMM: C(MxN) = A(MxK') * B(NxK')^T (K' slice), bf16 in ---
// EPI 0: +bias[col] -> bf16      EPI 1: +bias[row] -> bf16
// EPI 2: relu(+bias[col]) -> bf16  EPI 3: res + C + bias[col] -> fp32
// EPI 4: plain C -> fp32 (split-K partial; z=0 -> Cout, z=1 -> Cout2)
template<int EPI, int BN>
__global__ __launch_bounds__(256) void gemm_bt(
    const short* __restrict__ A, const short* __restrict__ Bm,
    void* __restrict__ Cout, void* __restrict__ Cout2,
    const float* __restrict__ bias, const float* __restrict__ res,
    int M, int N, int K, int lda, int ldb)
{
  __shared__ __align__(16) short As[128][32];
  __shared__ __align__(16) short Bs[BN][32];

  const int tid  = threadIdx.x;
  const int wave = tid >> 6, lane = tid & 63;
  const int l15  = lane & 15, l4 = lane >> 4;

  // XCD-aware bijective swizzle over full 3-D grid (nwg % 8 == 0 always here)
  const int gx = gridDim.x, gy = gridDim.y;
  int bid = (blockIdx.z * gy + blockIdx.y) * gx + blockIdx.x;
  const int q8 = (gx * gy * gridDim.z) >> 3;
  bid = (bid & 7) * q8 + (bid >> 3);
  const int n0 = (bid % gx) * BN;
  const int m0 = ((bid / gx) % gy) * 128;
  const int zi = bid / (gx * gy);
  const int koff = zi * K;

  constexpr int MI = (BN == 128) ? 4 : 2;
  const int rb = (BN == 128) ? (wave >> 1) * 64 : wave * 32;   // wave row base
  const int cb = (BN == 128) ? (wave & 1) * 64 : 0;            // wave col base

  float4_t acc[MI][4] = {};

  const int scol = (lane & 3) * 8;
  const short* gA0 = A + (size_t)(m0 + wave*32 + (lane >> 2)) * lda + koff + scol;
  const short* gA1 = gA0 + (size_t)16 * lda;
  const short* gB0;
  const short* gB1 = nullptr;
  if (BN == 128) {
    gB0 = Bm + (size_t)(n0 + wave*32 + (lane >> 2)) * ldb + koff + scol;
    gB1 = gB0 + (size_t)16 * ldb;
  } else {
    gB0 = Bm + (size_t)(n0 + wave*16 + (lane >> 2)) * ldb + koff + scol;
  }

  for (int k0 = 0; k0 < K; k0 += 32) {
    gload_lds16(gA0 + k0, &As[wave*32][0]);
    gload_lds16(gA1 + k0, &As[wave*32 + 16][0]);
    if (BN == 128) {
      gload_lds16(gB0 + k0, &Bs[wave*32][0]);
      gload_lds16(gB1 + k0, &Bs[wave*32 + 16][0]);
    } else {
      gload_lds16(gB0 + k0, &Bs[wave*16][0]);
    }
    __syncthreads();

    short8 af[MI], bf[4];
    #pragma unroll
    for (int i = 0; i < MI; i++)
      af[i] = *(const short8*)&As[rb + i*16 + l15][l4*8];
    #pragma unroll
    for (int i = 0; i < 4; i++)
      bf[i] = *(const short8*)&Bs[cb + i*16 + l15][l4*8];
    #pragma unroll
    for (int mi = 0; mi < MI; mi++)
      #pragma unroll
      for (int ni = 0; ni < 4; ni++)
        acc[mi][ni] = __builtin_amdgcn_mfma_f32_16x16x32_bf16(af[mi], bf[ni], acc[mi][ni], 0, 0, 0);
    __syncthreads();
  }

  const int crow0 = m0 + rb + l4*4;
  const int ccol0 = n0 + cb + l15;
  float* dstf = (float*)((EPI == 4 && zi == 1) ? Cout2 : Cout);
  #pragma unroll
  for (int mi = 0; mi < MI; mi++) {
    #pragma unroll
    for (int ni = 0; ni < 4; ni++) {
      const int col = ccol0 + ni*16;
      const float bc = (EPI == 1 || EPI == 4) ? 0.0f : bias[col];
      #pragma unroll
      for (int r = 0; r < 4; r++) {
        const int row = crow0 + mi*16 + r;
        const float v = acc[mi][ni][r];
        if (EPI == 0) {
          ((short*)Cout)[(size_t)row * N + col] = f2bf(v + bc);
        } else if (EPI == 1) {
          ((short*)Cout)[(size_t)row * N + col] = f2bf(v + bias[row]);
        } else if (EPI == 2) {
          ((short*)Cout)[(size_t)row * N + col] = f2bf(fmaxf(v + bc, 0.0f));
        } else if (EPI == 3) {
          ((float*)Cout)[(size_t)row * N + col] = res[(size_t)row * N + col] + v + bc;
        } else {
          dstf[(size_t)row * N + col] = v;
        }
      }
    }
  }
}

// ---------------- Flash attention (swapped QK^T, P fully in-register) ------
// qk: (TOK x 2048) bf16, Q cols [0,1024), K cols [1024,2048)  (col = h*64+d)
// vt: (1024 x TOK) bf16. maskb: (TOK) fp32 additive bias.
// 1024 blocks (64 q-rows), 4 waves x 16 q-rows. KVBLK=64, double-buffered.
// kf row permutation rho(kg,i)=32*(kg>>1)+8*(i>>2)+4*(kg&1)+(i&3) puts P's
// keys exactly in PV A-fragment slot order: P stays in registers.
// lsum via ones-column MFMA (P*1 = row sums, lands in C-layout: no trees,
// no shuffles, no epilogue broadcast).
#define SC2 0.18033688f   // (1/8) * log2(e)

__global__ __launch_bounds__(256, 4) void attn_kernel(
    const short* __restrict__ qk, const short* __restrict__ vt,
    const float* __restrict__ maskb, short* __restrict__ out)
{
  // XCD swizzle over linear block id (nwg = 1024)
  int bid = (blockIdx.z * H_ + blockIdx.y) * (S_/64) + blockIdx.x;
  bid = (bid & 7) * ((B_ * H_ * (S_/64)) >> 3) + (bid >> 3);
  const int qt = bid % (S_/64);
  const int h  = (bid / (S_/64)) % H_;
  const int b  = bid / ((S_/64) * H_);

  const int tid = threadIdx.x, wave = tid >> 6, lane = tid & 63;
  const int l15 = lane & 15, l4 = lane >> 4;
  const int q0 = qt * 64 + wave * 16;

  __shared__ __align__(16) short Kt[2][4096];
  __shared__ __align__(16) short Vt[2][4096];

  short8 qa[2];
  #pragma unroll
  for (int kc = 0; kc < 2; kc++)
    qa[kc] = *(const short8*)&qk[(size_t)(b*S_ + q0 + l15) * 2048 + h*64 + kc*32 + l4*8];

  // ones B-fragment for row-sum MFMA
  short8 ones;
  #pragma unroll
  for (int i = 0; i < 8; i++) ones[i] = (short)0x3F80;

  float4_t acc[4];
  #pragma unroll
  for (int dg = 0; dg < 4; dg++) acc[dg] = (float4_t){0.f, 0.f, 0.f, 0.f};
  float4_t accl = (float4_t){0.f, 0.f, 0.f, 0.f};
  float m2 = -1e30f;

  // staging: slot = i*256 + wave*64 + lane -> row = i*32 + wave*8 + (lane>>3)
  // source chunk = (lane&7) ^ g(row); g(row) = (r8&3) | ((wave&1)<<2)
  const int r8 = lane >> 3;
  const int ch = (lane & 7) ^ ((r8 & 3) | ((wave & 1) << 2));
  const int sbase = wave * 512;

  #pragma unroll
  for (int i = 0; i < 2; i++) {
    const int row = i*32 + wave*8 + r8;
    gload_lds16(qk + (size_t)(b*S_ + row) * 2048 + 1024 + h*64 + ch*8, &Kt[0][sbase + i*2048]);
    gload_lds16(vt + (size_t)(h*64 + row) * TOK + b*S_ + ch*8,         &Vt[0][sbase + i*2048]);
  }

  int krow[4];
  #pragma unroll
  for (int kg = 0; kg < 4; kg++)
    krow[kg] = 32*(kg>>1) + 8*(l15>>2) + 4*(kg&1) + (l15&3);
  const int gq = (l15 & 3) | (((l15 >> 2) & 1) << 2);
  const int gv = (l15 & 3) | (((l15 >> 3) & 1) << 2);

  for (int t = 0; t < S_/64; t++) {
    const int cur = t & 1;
    __syncthreads();   // drains vmcnt: tile t ready; prev compute done
    if (t + 1 < S_/64) {
      const int k1 = (t + 1) * 64;
      #pragma unroll
      for (int i = 0; i < 2; i++) {
        const int row = i*32 + wave*8 + r8;
        gload_lds16(qk + (size_t)(b*S_ + k1 + row) * 2048 + 1024 + h*64 + ch*8, &Kt[cur^1][sbase + i*2048]);
        gload_lds16(vt + (size_t)(h*64 + row) * TOK + b*S_ + k1 + ch*8,         &Vt[cur^1][sbase + i*2048]);
      }
    }
    const short* Kc = &Kt[cur][0];
    const short* Vc = &Vt[cur][0];

    short8 kf[4][2], vf[4][2];
    #pragma unroll
    for (int kg = 0; kg < 4; kg++)
      #pragma unroll
      for (int kc = 0; kc < 2; kc++)
        kf[kg][kc] = *(const short8*)(Kc + krow[kg]*64 + ((l4 + kc*4) ^ gq) * 8);
    #pragma unroll
    for (int dg = 0; dg < 4; dg++)
      #pragma unroll
      for (int pc = 0; pc < 2; pc++)
        vf[dg][pc] = *(const short8*)(Vc + (dg*16 + l15)*64 + ((l4 + pc*4) ^ gv) * 8);

    // mask bias at permuted keys: key(kg,r) = 32*(kg>>1) + 8*l4 + 4*(kg&1) + r
    float4_t mb[4];
    #pragma unroll
    for (int kg = 0; kg < 4; kg++)
      mb[kg] = *(const float4_t*)&maskb[b*S_ + t*64 + 32*(kg>>1) + 4*(kg&1) + 8*l4];

    float4_t sc[4];
    #pragma unroll
    for (int kg = 0; kg < 4; kg++) sc[kg] = (float4_t){0.f, 0.f, 0.f, 0.f};
    __builtin_amdgcn_s_setprio(1);
    #pragma unroll
    for (int kg = 0; kg < 4; kg++)
      #pragma unroll
      for (int kc = 0; kc < 2; kc++)
        sc[kg] = __builtin_amdgcn_mfma_f32_16x16x32_bf16(kf[kg][kc], qa[kc], sc[kg], 0, 0, 0);
    __builtin_amdgcn_s_setprio(0);
    #pragma unroll
    for (int kg = 0; kg < 4; kg++)
      #pragma unroll
      for (int r = 0; r < 4; r++)
        sc[kg][r] = sc[kg][r] * SC2 + mb[kg][r];
    // row max: max3-fusing chain + 2 shuffles across l4 groups
    float pm = fmaxf(fmaxf(sc[0][0], sc[0][1]), sc[0][2]);
    pm = fmaxf(fmaxf(pm, sc[0][3]), sc[1][0]);
    pm = fmaxf(fmaxf(pm, sc[1][1]), sc[1][2]);
    pm = fmaxf(fmaxf(pm, sc[1][3]), sc[2][0]);
    pm = fmaxf(fmaxf(pm, sc[2][1]), sc[2][2]);
    pm = fmaxf(fmaxf(pm, sc[2][3]), sc[3][0]);
    pm = fmaxf(fmaxf(pm, sc[3][1]), sc[3][2]);
    pm = fmaxf(pm, sc[3][3]);
    pm = fmaxf(pm, __shfl_xor(pm, 16));
    pm = fmaxf(pm, __shfl_xor(pm, 32));
    // defer-max (THR=8 in log2 units)
    if (__any(pm > m2 + 8.0f)) {
      const float nm  = fmaxf(m2, pm);
      const float esc = exp2f(m2 - nm);
      m2 = nm;
      #pragma unroll
      for (int r = 0; r < 4; r++) {
        const float er = __shfl(esc, l4*4 + r);
        #pragma unroll
        for (int dg = 0; dg < 4; dg++) acc[dg][r] *= er;
        accl[r] *= er;
      }
    }
    #pragma unroll
    for (int kg = 0; kg < 4; kg++)
      #pragma unroll
      for (int r = 0; r < 4; r++)
        sc[kg][r] = exp2f(sc[kg][r] - m2);
    // P -> bf16 A-fragments, fully in-register (keys already slot-ordered)
    union { short8 s8; uint32_t u[4]; } pu[2];
    #pragma unroll
    for (int pc = 0; pc < 2; pc++) {
      pu[pc].u[0] = pkbf(sc[2*pc][0],   sc[2*pc][1]);
      pu[pc].u[1] = pkbf(sc[2*pc][2],   sc[2*pc][3]);
      pu[pc].u[2] = pkbf(sc[2*pc+1][0], sc[2*pc+1][1]);
      pu[pc].u[3] = pkbf(sc[2*pc+1][2], sc[2*pc+1][3]);
    }
    __builtin_amdgcn_s_setprio(1);
    #pragma unroll
    for (int dg = 0; dg < 4; dg++)
      #pragma unroll
      for (int pc = 0; pc < 2; pc++)
        acc[dg] = __builtin_amdgcn_mfma_f32_16x16x32_bf16(pu[pc].s8, vf[dg][pc], acc[dg], 0, 0, 0);
    // row-sum MFMA: accl += P * ones
    #pragma unroll
    for (int pc = 0; pc < 2; pc++)
      accl = __builtin_amdgcn_mfma_f32_16x16x32_bf16(pu[pc].s8, ones, accl, 0, 0, 0);
    __builtin_amdgcn_s_setprio(0);
  }

  // accl[r] is the row sum for q-row l4*4+r (uniform across l15): no shuffles
  float linv[4];
  #pragma unroll
  for (int r = 0; r < 4; r++) linv[r] = 1.0f / accl[r];
  #pragma unroll
  for (int dg = 0; dg < 4; dg++)
    #pragma unroll
    for (int r = 0; r < 4; r++)
      out[(size_t)(b*S_ + q0 + l4*4 + r) * D_ + h*64 + dg*16 + l15] =
          f2bf(acc[dg][r] * linv[r]);
}

// ---------------------------------------------------------------------------
extern "C" void kernel_launch(void* const* d_in, const int* in_sizes, int n_in,
                              void* d_out, int out_size, void* d_ws, size_t ws_size,
                              hipStream_t stream)
{
  const float* x     = (const float*)d_in[0];
  const int*   mask  = (const int*)d_in[1];
  const float* wq_w  = (const float*)d_in[2];
  const float* wq_b  = (const float*)d_in[3];
  const float* wk_w  = (const float*)d_in[4];
  const float* wk_b  = (const float*)d_in[5];
  const float* wv_w  = (const float*)d_in[6];
  const float* wv_b  = (const float*)d_in[7];
  const float* wo_w  = (const float*)d_in[8];
  const float* wo_b  = (const float*)d_in[9];
  const float* ff1_w = (const float*)d_in[10];
  const float* ff1_b = (const float*)d_in[11];
  const float* ff2_w = (const float*)d_in[12];
  const float* ff2_b = (const float*)d_in[13];
  const float* ln1_a = (const float*)d_in[14];
  const float* ln1_b = (const float*)d_in[15];
  const float* ln2_a = (const float*)d_in[16];
  const float* ln2_b = (const float*)d_in[17];

  uint8_t* ws = (uint8_t*)d_ws;
  const size_t MB = 1024 * 1024;
  short* wqk   = (short*)(ws + 0);        // (2048,1024) bf16: [wq; wk]      4 MB
  short* wvb   = (short*)(ws + 4*MB);     // (1024,1024)                     2 MB
  short* wob   = (short*)(ws + 6*MB);     // (1024,1024)                     2 MB
  short* ff1b  = (short*)(ws + 8*MB);     // (4096,1024)                     8 MB
  short* ff2b  = (short*)(ws + 16*MB);    // (1024,4096)                     8 MB
  float* bqk   = (float*)(ws + 24*MB);    // 2048 fp32 concat bias           8 KB
  float* maskb = (float*)(ws + 24*MB + 64*1024);  // TOK fp32               16 KB
  short* h1    = (short*)(ws + 25*MB);    // (4096,1024) bf16 (h1, later h2) 8 MB
  short* qkbuf = (short*)(ws + 33*MB);    // (4096,2048) bf16               16 MB
  short* vt    = (short*)(ws + 49*MB);    // (1024,4096) bf16                8 MB
  short* attno = (short*)(ws + 57*MB);    // (4096,1024) bf16                8 MB
  float* x2    = (float*)(ws + 65*MB);    // (4096,1024) fp32               16 MB
  short* ffa   = (short*)(ws + 33*MB);    // (4096,4096) bf16 (reuses dead bufs)
  float* p0    = (float*)(ws + 0);        // FF2 split-K partial: reuses
                                          // wqk/wvb/wob/ff1b (all dead by FF2)

  // 1) weights -> bf16
  cvt_kernel<<<1024, 256, 0, stream>>>(wq_w, wqk,             1024*1024);
  cvt_kernel<<<1024, 256, 0, stream>>>(wk_w, wqk + 1024*1024, 1024*1024);
  cvt_kernel<<<1024, 256, 0, stream>>>(wv_w, wvb,             1024*1024);
  cvt_kernel<<<1024, 256, 0, stream>>>(wo_w, wob,             1024*1024);
  cvt_kernel<<<2048, 256, 0, stream>>>(ff1_w, ff1b,           4096*1024);
  cvt_kernel<<<2048, 256, 0, stream>>>(ff2_w, ff2b,           4096*1024);
  hipMemcpyAsync(bqk,        wq_b, 1024*sizeof(float), hipMemcpyDeviceToDevice, stream);
  hipMemcpyAsync(bqk + 1024, wk_b, 1024*sizeof(float), hipMemcpyDeviceToDevice, stream);
  maskb_kernel<<<TOK/256, 256, 0, stream>>>(mask, maskb, TOK);

  // 2) LN1: x -> h1 (bf16)
  ln_kernel<<<TOK, 256, 0, stream>>>(x, ln1_a, ln1_b, h1);

  // 3) [Q|K] = h1 @ [wq;wk]^T + b     (4096 x 2048), 512 blocks
  gemm_bt<0,128><<<dim3(2048/128, TOK/128), 256, 0, stream>>>(
      h1, wqk, qkbuf, nullptr, bqk, nullptr, TOK, 2048, 1024, 1024, 1024);

  // 4) V^T = wv @ h1^T + bv[row]      (1024 x 4096), BN=64 -> 512 blocks
  gemm_bt<1,64><<<dim3(TOK/64, 1024/128), 256, 0, stream>>>(
      wvb, h1, vt, nullptr, wv_b, nullptr, 1024, TOK, 1024, 1024, 1024);

  // 5) flash attention -> attno (bf16), 1024 blocks
  attn_kernel<<<dim3(S_/64, H_, B_), 256, 0, stream>>>(qkbuf, vt, maskb, attno);

  // 6) x2 = x + attno @ wo^T + bo     (fp32), BN=64 -> 512 blocks
  gemm_bt<3,64><<<dim3(1024/64, TOK/128), 256, 0, stream>>>(
      attno, wob, x2, nullptr, wo_b, x, TOK, 1024, 1024, 1024, 1024);

  // 7) LN2: x2 -> h2 (reuse h1 buffer)
  ln_kernel<<<TOK, 256, 0, stream>>>(x2, ln2_a, ln2_b, h1);

  // 8) ffa = relu(h2 @ ff1^T + b1)    (4096 x 4096 bf16), 1024 blocks
  gemm_bt<2,128><<<dim3(FF_/128, TOK/128), 256, 0, stream>>>(
      h1, ff1b, ffa, nullptr, ff1_b, nullptr, TOK, FF_, 1024, 1024, 1024);

  // 9) FF2 split-K=2, one launch: z=0 partial -> p0, z=1 partial -> d_out
  //    (4096 x 1024, K=2048 each, BN=128, 512 blocks = 2/CU)
  gemm_bt<4,128><<<dim3(1024/128, TOK/128, 2), 256, 0, stream>>>(
      ffa, ff2b, p0, d_out, nullptr, nullptr, TOK, 1024, 2048, FF_, FF_);

  // 10) out = x2 + b2 + p0 + out
  combine_kernel<<<2048, 256, 0, stream>>>(x2, p0, (float*)d_out, ff2_b, TOK * D_);
}

// Round 6
// 284.885 us; speedup vs baseline: 1.7531x; 1.0855x over previous
//
#include <hip/hip_runtime.h>
#include <hip/hip_bf16.h>
#include <stdint.h>

// Problem constants (B=2, S=2048, D=1024, H=16, DK=64, FF=4096)
#define B_   2
#define S_   2048
#define D_   1024
#define H_   16
#define FF_  4096
#define TOK  4096        // B*S
#define EPS_ 1e-5f
#define SC2  0.18033688f  // (1/8) * log2(e) -- folded into Q at projection

typedef __attribute__((ext_vector_type(8))) short short8;
typedef __attribute__((ext_vector_type(4))) short short4_t;
typedef __attribute__((ext_vector_type(4))) float float4_t;

__device__ __forceinline__ short f2bf(float f) {
  union { float f; uint32_t u; } v; v.f = f;
  uint32_t r = v.u + 0x7fffu + ((v.u >> 16) & 1u);
  return (short)(r >> 16);
}

// packed f32x2 -> bf16x2 (compiler emits v_cvt_pk_bf16_f32; RNE)
__device__ __forceinline__ uint32_t pkbf(float a, float b) {
  __hip_bfloat162 h = __float22bfloat162_rn(make_float2(a, b));   // x=low=a
  union { __hip_bfloat162 h; uint32_t u; } c; c.h = h; return c.u;
}

__device__ __forceinline__ void gload_lds16(const void* g, void* l) {
  __builtin_amdgcn_global_load_lds(
      (const __attribute__((address_space(1))) void*)g,
      (__attribute__((address_space(3))) void*)l, 16, 0, 0);
}

// ---------------- merged fp32 -> bf16 conversion of ALL weights ------------
// dest layout (shorts): [wq 1M][wk 1M][wv 1M][wo 1M][ff1 4M][ff2 4M] = 12M
__global__ void cvt_all(const float* __restrict__ wq, const float* __restrict__ wk,
                        const float* __restrict__ wv, const float* __restrict__ wo,
                        const float* __restrict__ f1, const float* __restrict__ f2,
                        short* __restrict__ out) {
  const int n4 = (12 << 20) / 4;
  int idx = blockIdx.x * blockDim.x + threadIdx.x;
  int stride = gridDim.x * blockDim.x;
  for (int j4 = idx; j4 < n4; j4 += stride) {
    const int j = j4 * 4;
    const int seg = j >> 20;
    const float* src; int off;
    if (seg < 4)      { src = (seg == 0) ? wq : (seg == 1) ? wk : (seg == 2) ? wv : wo;
                        off = j & ((1 << 20) - 1); }
    else if (seg < 8) { src = f1; off = j - (4 << 20); }
    else              { src = f2; off = j - (8 << 20); }
    float4_t v = *(const float4_t*)(src + off);
    short4_t o = { f2bf(v[0]), f2bf(v[1]), f2bf(v[2]), f2bf(v[3]) };
    *(short4_t*)(out + j) = o;
  }
}

// ---------------- mask -> additive bias + per-64-key-tile flags ------------
__global__ void mask_kernel(const int* __restrict__ m, float* __restrict__ o,
                            int* __restrict__ flags) {
  const int i = blockIdx.x * 64 + threadIdx.x;
  const int mv = m[i];
  o[i] = mv ? 0.0f : -1e30f;
  unsigned long long bal = __ballot(mv == 0);
  if (threadIdx.x == 0) flags[blockIdx.x] = (bal != 0ull) ? 1 : 0;
}

// ---------------- split-K combine: out = x2 + bias + p0 + out --------------
__global__ void combine_kernel(const float* __restrict__ x2, const float* __restrict__ p0,
                               float* __restrict__ out, const float* __restrict__ bias, int n) {
  int idx = blockIdx.x * blockDim.x + threadIdx.x;
  int stride = gridDim.x * blockDim.x;
  for (int j = idx * 4; j < n; j += stride * 4) {
    float4_t a = *(const float4_t*)(x2 + j);
    float4_t b = *(const float4_t*)(p0 + j);
    float4_t c = *(const float4_t*)(out + j);
    float4_t bb = *(const float4_t*)(bias + (j & (D_ - 1)));
    float4_t o = { a[0]+b[0]+c[0]+bb[0], a[1]+b[1]+c[1]+bb[1],
                   a[2]+b[2]+c[2]+bb[2], a[3]+b[3]+c[3]+bb[3] };
    *(float4_t*)(out + j) = o;
  }
}

// ---------------- LayerNorm (ddof=1, divide by std+eps), f32 in, bf16 out --
__global__ __launch_bounds__(256) void ln_kernel(
    const float* __restrict__ x, const float* __restrict__ alpha,
    const float* __restrict__ beta, short* __restrict__ out)
{
  const int row = blockIdx.x;
  const int tid = threadIdx.x;
  const float4_t v = *(const float4_t*)(x + (size_t)row * D_ + tid * 4);
  float s  = v[0] + v[1] + v[2] + v[3];
  float ss = v[0]*v[0] + v[1]*v[1] + v[2]*v[2] + v[3]*v[3];
  #pragma unroll
  for (int m = 1; m < 64; m <<= 1) { s += __shfl_xor(s, m); ss += __shfl_xor(ss, m); }
  __shared__ float red[8];
  const int wave = tid >> 6, lane = tid & 63;
  if (lane == 0) { red[wave] = s; red[4 + wave] = ss; }
  __syncthreads();
  s  = red[0] + red[1] + red[2] + red[3];
  ss = red[4] + red[5] + red[6] + red[7];
  const float mean = s * (1.0f / D_);
  float var = (ss - (float)D_ * mean * mean) * (1.0f / (D_ - 1));
  var = fmaxf(var, 0.0f);
  const float inv = 1.0f / (sqrtf(var) + EPS_);
  short4_t o;
  #pragma unroll
  for (int j = 0; j < 4; j++) {
    float a = alpha[tid*4 + j], bb = beta[tid*4 + j];
    o[j] = f2bf((v[j] - mean) * inv * a + bb);
  }
  *(short4_t*)(out + (size_t)row * D_ + tid * 4) = o;
}

// ---------------- GEMM: C(MxN) = A * B^T, single-barrier LDS double-buffer -
// EPI 2: relu(+bias[col]) -> bf16   EPI 3: res + C + bias[col] -> fp32
// EPI 4: plain C -> fp32 (split-K partial; z=0 -> Cout, z=1 -> Cout2)
template<int EPI, int BN>
__global__ __launch_bounds__(256) void gemm_bt(
    const short* __restrict__ A, const short* __restrict__ Bm,
    void* __restrict__ Cout, void* __restrict__ Cout2,
    const float* __restrict__ bias, const float* __restrict__ res,
    int N, int K, int lda, int ldb)
{
  __shared__ __align__(16) short As[2][128][32];
  __shared__ __align__(16) short Bs[2][BN][32];

  const int tid  = threadIdx.x;
  const int wave = tid >> 6, lane = tid & 63;
  const int l15  = lane & 15, l4 = lane >> 4;

  // XCD-aware bijective swizzle over full 3-D grid (nwg % 8 == 0 always here)
  const int gx = gridDim.x, gy = gridDim.y;
  int bid = (blockIdx.z * gy + blockIdx.y) * gx + blockIdx.x;
  const int q8 = (gx * gy * gridDim.z) >> 3;
  bid = (bid & 7) * q8 + (bid >> 3);
  const int n0 = (bid % gx) * BN;
  const int m0 = ((bid / gx) % gy) * 128;
  const int zi = bid / (gx * gy);
  const int koff = zi * K;

  constexpr int MI = (BN == 128) ? 4 : 2;
  const int rb = (BN == 128) ? (wave >> 1) * 64 : wave * 32;
  const int cb = (BN == 128) ? (wave & 1) * 64 : 0;

  float4_t acc[MI][4] = {};

  const int scol = (lane & 3) * 8;
  const short* gA0 = A + (size_t)(m0 + wave*32 + (lane >> 2)) * lda + koff + scol;
  const short* gA1 = gA0 + (size_t)16 * lda;
  const short* gB0;
  const short* gB1 = nullptr;
  if (BN == 128) {
    gB0 = Bm + (size_t)(n0 + wave*32 + (lane >> 2)) * ldb + koff + scol;
    gB1 = gB0 + (size_t)16 * ldb;
  } else {
    gB0 = Bm + (size_t)(n0 + wave*16 + (lane >> 2)) * ldb + koff + scol;
  }

  // prologue: stage k-tile 0 into buffer 0
  gload_lds16(gA0, &As[0][wave*32][0]);
  gload_lds16(gA1, &As[0][wave*32 + 16][0]);
  if (BN == 128) {
    gload_lds16(gB0, &Bs[0][wave*32][0]);
    gload_lds16(gB1, &Bs[0][wave*32 + 16][0]);
  } else {
    gload_lds16(gB0, &Bs[0][wave*16][0]);
  }

  for (int k0 = 0; k0 < K; k0 += 32) {
    const int cur = (k0 >> 5) & 1;
    __syncthreads();   // vmcnt(0)+barrier: buf[cur] staged, prev reads done
    if (k0 + 32 < K) {   // stage next tile; overlaps with MFMA below
      gload_lds16(gA0 + k0 + 32, &As[cur^1][wave*32][0]);
      gload_lds16(gA1 + k0 + 32, &As[cur^1][wave*32 + 16][0]);
      if (BN == 128) {
        gload_lds16(gB0 + k0 + 32, &Bs[cur^1][wave*32][0]);
        gload_lds16(gB1 + k0 + 32, &Bs[cur^1][wave*32 + 16][0]);
      } else {
        gload_lds16(gB0 + k0 + 32, &Bs[cur^1][wave*16][0]);
      }
    }
    short8 af[MI], bf[4];
    #pragma unroll
    for (int i = 0; i < MI; i++)
      af[i] = *(const short8*)&As[cur][rb + i*16 + l15][l4*8];
    #pragma unroll
    for (int i = 0; i < 4; i++)
      bf[i] = *(const short8*)&Bs[cur][cb + i*16 + l15][l4*8];
    #pragma unroll
    for (int mi = 0; mi < MI; mi++)
      #pragma unroll
      for (int ni = 0; ni < 4; ni++)
        acc[mi][ni] = __builtin_amdgcn_mfma_f32_16x16x32_bf16(af[mi], bf[ni], acc[mi][ni], 0, 0, 0);
  }

  const int crow0 = m0 + rb + l4*4;
  const int ccol0 = n0 + cb + l15;
  float* dstf = (float*)((EPI == 4 && zi == 1) ? Cout2 : Cout);
  #pragma unroll
  for (int mi = 0; mi < MI; mi++) {
    #pragma unroll
    for (int ni = 0; ni < 4; ni++) {
      const int col = ccol0 + ni*16;
      const float bc = (EPI == 4) ? 0.0f : bias[col];
      #pragma unroll
      for (int r = 0; r < 4; r++) {
        const int row = crow0 + mi*16 + r;
        const float v = acc[mi][ni][r];
        if (EPI == 2) {
          ((short*)Cout)[(size_t)row * N + col] = f2bf(fmaxf(v + bc, 0.0f));
        } else if (EPI == 3) {
          ((float*)Cout)[(size_t)row * N + col] = res[(size_t)row * N + col] + v + bc;
        } else {
          dstf[(size_t)row * N + col] = v;
        }
      }
    }
  }
}

// ---------------- fused QKV GEMM: [Q|K|V] = h1 @ [wq;wk;wv]^T + bias -------
// N=3072, M=TOK, K=1024, BN=128, grid (24,32)=768 blocks.
// Q cols (0..1023):   qkbuf[row][col]      = (v + qb[col]) * SC2  (pre-scaled!)
// K cols (1024..2047): qkbuf[row][col]     = v + kb[col-1024]
// V cols (2048..3071): vt[col-2048][row]   = v + vb[col-2048]  (transposed scatter)
__global__ __launch_bounds__(256) void qkv_gemm(
    const short* __restrict__ A, const short* __restrict__ Bm,
    short* __restrict__ qkbuf, short* __restrict__ vt,
    const float* __restrict__ qb, const float* __restrict__ kb,
    const float* __restrict__ vb)
{
  __shared__ __align__(16) short As[2][128][32];
  __shared__ __align__(16) short Bs[2][128][32];

  const int tid  = threadIdx.x;
  const int wave = tid >> 6, lane = tid & 63;
  const int l15  = lane & 15, l4 = lane >> 4;

  const int gx = gridDim.x;
  int bid = blockIdx.y * gx + blockIdx.x;
  const int q8 = (gx * gridDim.y) >> 3;
  bid = (bid & 7) * q8 + (bid >> 3);
  const int n0 = (bid % gx) * 128;
  const int m0 = (bid / gx) * 128;

  const int rb = (wave >> 1) * 64;
  const int cb = (wave & 1) * 64;

  float4_t acc[4][4] = {};

  const int scol = (lane & 3) * 8;
  const short* gA0 = A  + (size_t)(m0 + wave*32 + (lane >> 2)) * 1024 + scol;
  const short* gA1 = gA0 + (size_t)16 * 1024;
  const short* gB0 = Bm + (size_t)(n0 + wave*32 + (lane >> 2)) * 1024 + scol;
  const short* gB1 = gB0 + (size_t)16 * 1024;

  gload_lds16(gA0, &As[0][wave*32][0]);
  gload_lds16(gA1, &As[0][wave*32 + 16][0]);
  gload_lds16(gB0, &Bs[0][wave*32][0]);
  gload_lds16(gB1, &Bs[0][wave*32 + 16][0]);

  for (int k0 = 0; k0 < 1024; k0 += 32) {
    const int cur = (k0 >> 5) & 1;
    __syncthreads();
    if (k0 + 32 < 1024) {
      gload_lds16(gA0 + k0 + 32, &As[cur^1][wave*32][0]);
      gload_lds16(gA1 + k0 + 32, &As[cur^1][wave*32 + 16][0]);
      gload_lds16(gB0 + k0 + 32, &Bs[cur^1][wave*32][0]);
      gload_lds16(gB1 + k0 + 32, &Bs[cur^1][wave*32 + 16][0]);
    }
    short8 af[4], bf[4];
    #pragma unroll
    for (int i = 0; i < 4; i++)
      af[i] = *(const short8*)&As[cur][rb + i*16 + l15][l4*8];
    #pragma unroll
    for (int i = 0; i < 4; i++)
      bf[i] = *(const short8*)&Bs[cur][cb + i*16 + l15][l4*8];
    #pragma unroll
    for (int mi = 0; mi < 4; mi++)
      #pragma unroll
      for (int ni = 0; ni < 4; ni++)
        acc[mi][ni] = __builtin_amdgcn_mfma_f32_16x16x32_bf16(af[mi], bf[ni], acc[mi][ni], 0, 0, 0);
  }

  const int crow0 = m0 + rb + l4*4;
  const int ccol0 = n0 + cb + l15;
  const int seg = n0 >> 10;   // 0=Q, 1=K, 2=V (uniform per block: 1024%128==0)
  if (seg < 2) {
    const float* bb = seg ? kb : qb;
    const float scl = seg ? 1.0f : SC2;
    #pragma unroll
    for (int mi = 0; mi < 4; mi++)
      #pragma unroll
      for (int ni = 0; ni < 4; ni++) {
        const int col = ccol0 + ni*16;
        const float bc = bb[col & 1023];
        #pragma unroll
        for (int r = 0; r < 4; r++)
          qkbuf[(size_t)(crow0 + mi*16 + r) * 2048 + col] =
              f2bf((acc[mi][ni][r] + bc) * scl);
      }
  } else {
    #pragma unroll
    for (int mi = 0; mi < 4; mi++)
      #pragma unroll
      for (int ni = 0; ni < 4; ni++) {
        const int d = ccol0 + ni*16 - 2048;
        const float bc = vb[d];
        short4_t o = { f2bf(acc[mi][ni][0] + bc), f2bf(acc[mi][ni][1] + bc),
                       f2bf(acc[mi][ni][2] + bc), f2bf(acc[mi][ni][3] + bc) };
        *(short4_t*)&vt[(size_t)d * TOK + crow0 + mi*16] = o;
      }
  }
}

// ---------------- Flash attention (swapped QK^T, P fully in-register) ------
// qk: (TOK x 2048) bf16, pre-scaled Q cols [0,1024), K cols [1024,2048)
// vt: (1024 x TOK) bf16. maskb: additive bias; mflags: per-64-key-tile flags.
// Scores arrive in log2 domain (Q pre-scaled by SC2). -m2 folded into the
// QK MFMA C-initializer: sc = s - m2 directly; defer-max trigger pm > 8.
__global__ __launch_bounds__(256, 4) void attn_kernel(
    const short* __restrict__ qk, const short* __restrict__ vt,
    const float* __restrict__ maskb, const int* __restrict__ mflags,
    short* __restrict__ out)
{
  int bid = (blockIdx.z * H_ + blockIdx.y) * (S_/64) + blockIdx.x;
  bid = (bid & 7) * ((B_ * H_ * (S_/64)) >> 3) + (bid >> 3);
  const int qt = bid % (S_/64);
  const int h  = (bid / (S_/64)) % H_;
  const int b  = bid / ((S_/64) * H_);

  const int tid = threadIdx.x, wave = tid >> 6, lane = tid & 63;
  const int l15 = lane & 15, l4 = lane >> 4;
  const int q0 = qt * 64 + wave * 16;

  __shared__ __align__(16) short Kt[2][4096];
  __shared__ __align__(16) short Vt[2][4096];

  short8 qa[2];
  #pragma unroll
  for (int kc = 0; kc < 2; kc++)
    qa[kc] = *(const short8*)&qk[(size_t)(b*S_ + q0 + l15) * 2048 + h*64 + kc*32 + l4*8];

  short8 ones;
  #pragma unroll
  for (int i = 0; i < 8; i++) ones[i] = (short)0x3F80;

  float4_t acc[4];
  #pragma unroll
  for (int dg = 0; dg < 4; dg++) acc[dg] = (float4_t){0.f, 0.f, 0.f, 0.f};
  float4_t accl = (float4_t){0.f, 0.f, 0.f, 0.f};
  float m2 = 0.0f;   // running max in log2 units (defer-max, P <= 2^8 bounded)

  const int r8 = lane >> 3;
  const int ch = (lane & 7) ^ ((r8 & 3) | ((wave & 1) << 2));
  const int sbase = wave * 512;

  #pragma unroll
  for (int i = 0; i < 2; i++) {
    const int row = i*32 + wave*8 + r8;
    gload_lds16(qk + (size_t)(b*S_ + row) * 2048 + 1024 + h*64 + ch*8, &Kt[0][sbase + i*2048]);
    gload_lds16(vt + (size_t)(h*64 + row) * TOK + b*S_ + ch*8,         &Vt[0][sbase + i*2048]);
  }

  int krow[4];
  #pragma unroll
  for (int kg = 0; kg < 4; kg++)
    krow[kg] = 32*(kg>>1) + 8*(l15>>2) + 4*(kg&1) + (l15&3);
  const int gq = (l15 & 3) | (((l15 >> 2) & 1) << 2);
  const int gv = (l15 & 3) | (((l15 >> 3) & 1) << 2);

  for (int t = 0; t < S_/64; t++) {
    const int cur = t & 1;
    __syncthreads();   // vmcnt(0)+barrier: tile t staged, prev compute done
    if (t + 1 < S_/64) {
      const int k1 = (t + 1) * 64;
      #pragma unroll
      for (int i = 0; i < 2; i++) {
        const int row = i*32 + wave*8 + r8;
        gload_lds16(qk + (size_t)(b*S_ + k1 + row) * 2048 + 1024 + h*64 + ch*8, &Kt[cur^1][sbase + i*2048]);
        gload_lds16(vt + (size_t)(h*64 + row) * TOK + b*S_ + k1 + ch*8,         &Vt[cur^1][sbase + i*2048]);
      }
    }
    const short* Kc = &Kt[cur][0];
    const short* Vc = &Vt[cur][0];

    short8 kf[4][2], vf[4][2];
    #pragma unroll
    for (int kg = 0; kg < 4; kg++)
      #pragma unroll
      for (int kc = 0; kc < 2; kc++)
        kf[kg][kc] = *(const short8*)(Kc + krow[kg]*64 + ((l4 + kc*4) ^ gq) * 8);
    #pragma unroll
    for (int dg = 0; dg < 4; dg++)
      #pragma unroll
      for (int pc = 0; pc < 2; pc++)
        vf[dg][pc] = *(const short8*)(Vc + (dg*16 + l15)*64 + ((l4 + pc*4) ^ gv) * 8);

    // QK^T with C initialized to -m2: sc = score - m2 (per-lane q = l15)
    const float negm2 = -m2;
    float4_t sc[4];
    #pragma unroll
    for (int kg = 0; kg < 4; kg++)
      sc[kg] = (float4_t){negm2, negm2, negm2, negm2};
    __builtin_amdgcn_s_setprio(1);
    #pragma unroll
    for (int kg = 0; kg < 4; kg++)
      #pragma unroll
      for (int kc = 0; kc < 2; kc++)
        sc[kg] = __builtin_amdgcn_mfma_f32_16x16x32_bf16(kf[kg][kc], qa[kc], sc[kg], 0, 0, 0);
    __builtin_amdgcn_s_setprio(0);

    // mask (rare path; key(kg,r) = 32*(kg>>1) + 8*l4 + 4*(kg&1) + r)
    if (mflags[b*(S_/64) + t]) {
      #pragma unroll
      for (int kg = 0; kg < 4; kg++) {
        float4_t mb = *(const float4_t*)&maskb[b*S_ + t*64 + 32*(kg>>1) + 4*(kg&1) + 8*l4];
        #pragma unroll
        for (int r = 0; r < 4; r++) sc[kg][r] += mb[r];
      }
    }

    // per-q max of shifted scores (lane's 16 + 2 shuffles across l4 groups)
    float pm = fmaxf(fmaxf(sc[0][0], sc[0][1]), sc[0][2]);
    pm = fmaxf(fmaxf(pm, sc[0][3]), sc[1][0]);
    pm = fmaxf(fmaxf(pm, sc[1][1]), sc[1][2]);
    pm = fmaxf(fmaxf(pm, sc[1][3]), sc[2][0]);
    pm = fmaxf(fmaxf(pm, sc[2][1]), sc[2][2]);
    pm = fmaxf(fmaxf(pm, sc[2][3]), sc[3][0]);
    pm = fmaxf(fmaxf(pm, sc[3][1]), sc[3][2]);
    pm = fmaxf(pm, sc[3][3]);
    pm = fmaxf(pm, __shfl_xor(pm, 16));
    pm = fmaxf(pm, __shfl_xor(pm, 32));
    // defer-max: rescale only when shifted max exceeds 8 (rare)
    if (__any(pm > 8.0f)) {
      const float shift = fmaxf(pm, 0.0f);
      m2 += shift;
      const float esc = exp2f(-shift);
      #pragma unroll
      for (int r = 0; r < 4; r++) {
        const float er = __shfl(esc, l4*4 + r);
        #pragma unroll
        for (int dg = 0; dg < 4; dg++) acc[dg][r] *= er;
        accl[r] *= er;
      }
      #pragma unroll
      for (int kg = 0; kg < 4; kg++)
        #pragma unroll
        for (int r = 0; r < 4; r++) sc[kg][r] -= shift;
    }
    // P = 2^sc directly (no per-element sub in the common path)
    #pragma unroll
    for (int kg = 0; kg < 4; kg++)
      #pragma unroll
      for (int r = 0; r < 4; r++)
        sc[kg][r] = exp2f(sc[kg][r]);

    union { short8 s8; uint32_t u[4]; } pu[2];
    #pragma unroll
    for (int pc = 0; pc < 2; pc++) {
      pu[pc].u[0] = pkbf(sc[2*pc][0],   sc[2*pc][1]);
      pu[pc].u[1] = pkbf(sc[2*pc][2],   sc[2*pc][3]);
      pu[pc].u[2] = pkbf(sc[2*pc+1][0], sc[2*pc+1][1]);
      pu[pc].u[3] = pkbf(sc[2*pc+1][2], sc[2*pc+1][3]);
    }
    __builtin_amdgcn_s_setprio(1);
    #pragma unroll
    for (int dg = 0; dg < 4; dg++)
      #pragma unroll
      for (int pc = 0; pc < 2; pc++)
        acc[dg] = __builtin_amdgcn_mfma_f32_16x16x32_bf16(pu[pc].s8, vf[dg][pc], acc[dg], 0, 0, 0);
    #pragma unroll
    for (int pc = 0; pc < 2; pc++)
      accl = __builtin_amdgcn_mfma_f32_16x16x32_bf16(pu[pc].s8, ones, accl, 0, 0, 0);
    __builtin_amdgcn_s_setprio(0);
  }

  float linv[4];
  #pragma unroll
  for (int r = 0; r < 4; r++) linv[r] = 1.0f / accl[r];
  #pragma unroll
  for (int dg = 0; dg < 4; dg++)
    #pragma unroll
    for (int r = 0; r < 4; r++)
      out[(size_t)(b*S_ + q0 + l4*4 + r) * D_ + h*64 + dg*16 + l15] =
          f2bf(acc[dg][r] * linv[r]);
}

// ---------------------------------------------------------------------------
extern "C" void kernel_launch(void* const* d_in, const int* in_sizes, int n_in,
                              void* d_out, int out_size, void* d_ws, size_t ws_size,
                              hipStream_t stream)
{
  const float* x     = (const float*)d_in[0];
  const int*   mask  = (const int*)d_in[1];
  const float* wq_w  = (const float*)d_in[2];
  const float* wq_b  = (const float*)d_in[3];
  const float* wk_w  = (const float*)d_in[4];
  const float* wk_b  = (const float*)d_in[5];
  const float* wv_w  = (const float*)d_in[6];
  const float* wv_b  = (const float*)d_in[7];
  const float* wo_w  = (const float*)d_in[8];
  const float* wo_b  = (const float*)d_in[9];
  const float* ff1_w = (const float*)d_in[10];
  const float* ff1_b = (const float*)d_in[11];
  const float* ff2_w = (const float*)d_in[12];
  const float* ff2_b = (const float*)d_in[13];
  const float* ln1_a = (const float*)d_in[14];
  const float* ln1_b = (const float*)d_in[15];
  const float* ln2_a = (const float*)d_in[16];
  const float* ln2_b = (const float*)d_in[17];

  uint8_t* ws = (uint8_t*)d_ws;
  const size_t MB = 1024 * 1024;
  short* wqkv  = (short*)(ws + 0);        // (3072,1024) bf16 [wq;wk;wv]     6 MB
  short* wob   = (short*)(ws + 6*MB);     // (1024,1024)                     2 MB
  short* ff1b  = (short*)(ws + 8*MB);     // (4096,1024)                     8 MB
  short* ff2b  = (short*)(ws + 16*MB);    // (1024,4096)                     8 MB
  float* maskb = (float*)(ws + 24*MB + 64*1024);   // TOK fp32             16 KB
  int*   mflg  = (int*)(ws + 24*MB + 128*1024);    // TOK/64 ints
  short* h1    = (short*)(ws + 25*MB);    // (4096,1024) bf16 (h1, later h2) 8 MB
  short* qkbuf = (short*)(ws + 33*MB);    // (4096,2048) bf16               16 MB
  short* vt    = (short*)(ws + 49*MB);    // (1024,4096) bf16                8 MB
  short* attno = (short*)(ws + 57*MB);    // (4096,1024) bf16                8 MB
  float* x2    = (float*)(ws + 65*MB);    // (4096,1024) fp32               16 MB
  short* ffa   = (short*)(ws + 33*MB);    // (4096,4096) bf16 (reuses dead bufs)
  float* p0    = (float*)(ws + 0);        // FF2 partial (weights dead by then)

  // 1) all weights -> bf16 (one launch)
  cvt_all<<<2048, 256, 0, stream>>>(wq_w, wk_w, wv_w, wo_w, ff1_w, ff2_w, (short*)ws);
  // 2) mask bias + per-tile flags
  mask_kernel<<<TOK/64, 64, 0, stream>>>(mask, maskb, mflg);
  // 3) LN1: x -> h1 (bf16)
  ln_kernel<<<TOK, 256, 0, stream>>>(x, ln1_a, ln1_b, h1);
  // 4) fused [Q|K|V] projection (Q pre-scaled, V written transposed)
  qkv_gemm<<<dim3(3072/128, TOK/128), 256, 0, stream>>>(
      h1, wqkv, qkbuf, vt, wq_b, wk_b, wv_b);
  // 5) flash attention -> attno (bf16), 1024 blocks
  attn_kernel<<<dim3(S_/64, H_, B_), 256, 0, stream>>>(qkbuf, vt, maskb, mflg, attno);
  // 6) x2 = x + attno @ wo^T + bo     (fp32), BN=64 -> 512 blocks
  gemm_bt<3,64><<<dim3(1024/64, TOK/128), 256, 0, stream>>>(
      attno, wob, x2, nullptr, wo_b, x, 1024, 1024, 1024, 1024);
  // 7) LN2: x2 -> h2 (reuse h1 buffer)
  ln_kernel<<<TOK, 256, 0, stream>>>(x2, ln2_a, ln2_b, h1);
  // 8) ffa = relu(h2 @ ff1^T + b1)    (4096 x 4096 bf16), 1024 blocks
  gemm_bt<2,128><<<dim3(FF_/128, TOK/128), 256, 0, stream>>>(
      h1, ff1b, ffa, nullptr, ff1_b, nullptr, FF_, 1024, 1024, 1024);
  // 9) FF2 split-K=2: z=0 partial -> p0, z=1 partial -> d_out
  gemm_bt<4,128><<<dim3(1024/128, TOK/128, 2), 256, 0, stream>>>(
      ffa, ff2b, p0, d_out, nullptr, nullptr, 1024, 2048, FF_, FF_);
  // 10) out = x2 + b2 + p0 + out
  combine_kernel<<<2048, 256, 0, stream>>>(x2, p0, (float*)d_out, ff2_b, TOK * D_);
}